// Round 8
// baseline (2092.641 us; speedup 1.0000x reference)
//
#include <hip/hip_runtime.h>
#include <hip/hip_fp16.h>

#define NG 100000
#define NDR 10000
#define NDI 5000
#define NDOM (3 * NG + NDR + NDI)   // 315000 combined node domain
#define NBUCK 616                   // cdiv(NDOM, 512)
#define NBSMALL 586                 // buckets below 3*NG (small caps)
#define CAP_S 8192
#define CAP_L 32768

typedef _Float16 f16x8 __attribute__((ext_vector_type(8)));
typedef float f32x4 __attribute__((ext_vector_type(4)));

__device__ __forceinline__ void atomAddF(float* p, float v) { unsafeAtomicAdd(p, v); }

static inline int cdiv_h(int a, int b) { return (a + b - 1) / b; }

__device__ __forceinline__ size_t bbase(int b) {
  return b < NBSMALL ? (size_t)b * CAP_S
                     : (size_t)NBSMALL * CAP_S + (size_t)(b - NBSMALL) * CAP_L;
}
__device__ __forceinline__ int bcap(int b) { return b < NBSMALL ? CAP_S : CAP_L; }

// ---------------- pass A: bin (node,val) pairs into buckets + count degrees ----------------
__device__ __forceinline__ void emitPair(unsigned node, unsigned val,
                                         unsigned* __restrict__ deg,
                                         int* __restrict__ bcur,
                                         uint2* __restrict__ pairs) {
  atomicAdd(&deg[node], 1u);
  int b = node >> 9;
  int p = atomicAdd(&bcur[b], 1);
  if (p < bcap(b)) pairs[bbase(b) + p] = make_uint2(node, val);
}

__global__ __launch_bounds__(256) void k_binA(const int* __restrict__ ge, int Eg_,
                                              const int* __restrict__ de, int Ed_,
                                              const int* __restrict__ ce, int Ec_,
                                              unsigned* __restrict__ deg,
                                              int* __restrict__ bcur,
                                              uint2* __restrict__ pairs) {
  int nb_g = (Eg_ + 255) >> 8, nb_d = (Ed_ + 255) >> 8;
  int blk = blockIdx.x;
  if (blk < nb_g) {
    int e = blk * 256 + threadIdx.x;
    if (e < Eg_) emitPair((unsigned)ge[Eg_ + e], (unsigned)ge[e], deg, bcur, pairs);
  } else if (blk < nb_g + nb_d) {
    int e = (blk - nb_g) * 256 + threadIdx.x;
    if (e < Ed_) {
      unsigned s = de[e], d = de[Ed_ + e];
      emitPair(NG + d, s, deg, bcur, pairs);
      emitPair(3 * NG + s, d, deg, bcur, pairs);
    }
  } else {
    int e = (blk - nb_g - nb_d) * 256 + threadIdx.x;
    if (e < Ec_) {
      unsigned s = ce[e], d = ce[Ec_ + e];
      emitPair(2 * NG + d, s, deg, bcur, pairs);
      emitPair(3 * NG + NDR + s, d, deg, bcur, pairs);
    }
  }
}

// ---------------- scan (1024 elems/block) ----------------
__global__ __launch_bounds__(256) void k_blocksum4(const unsigned* __restrict__ deg,
                                                   unsigned* __restrict__ partial, int n) {
  __shared__ unsigned s[256];
  int t = threadIdx.x;
  int base = blockIdx.x * 1024 + t * 4;
  unsigned v = 0;
  if (base + 3 < n) {
    uint4 u = *(const uint4*)&deg[base];
    v = u.x + u.y + u.z + u.w;
  } else {
    for (int j = 0; j < 4; j++)
      if (base + j < n) v += deg[base + j];
  }
  s[t] = v;
  __syncthreads();
  for (int off = 128; off; off >>= 1) {
    if (t < off) s[t] += s[t + off];
    __syncthreads();
  }
  if (!t) partial[blockIdx.x] = s[0];
}

__global__ __launch_bounds__(512) void k_scanpart(unsigned* __restrict__ partial, int nb) {
  __shared__ unsigned s[512];
  int t = threadIdx.x;
  unsigned v = (t < nb) ? partial[t] : 0u;
  s[t] = v;
  __syncthreads();
  for (int off = 1; off < 512; off <<= 1) {
    unsigned add = (t >= off) ? s[t - off] : 0u;
    __syncthreads();
    s[t] += add;
    __syncthreads();
  }
  if (t < nb) partial[t] = s[t] - v;  // exclusive
}

__global__ __launch_bounds__(256) void k_rowptrAll(const unsigned* __restrict__ deg,
                                                   const unsigned* __restrict__ partial, int n,
                                                   int* __restrict__ rowptr,
                                                   float* __restrict__ dis) {
  __shared__ unsigned s[256];
  int t = threadIdx.x;
  int base = blockIdx.x * 1024 + t * 4;
  unsigned v[4] = {0u, 0u, 0u, 0u};
  if (base + 3 < n) {
    uint4 u = *(const uint4*)&deg[base];
    v[0] = u.x; v[1] = u.y; v[2] = u.z; v[3] = u.w;
  } else {
    for (int j = 0; j < 4; j++)
      if (base + j < n) v[j] = deg[base + j];
  }
  unsigned sum4 = v[0] + v[1] + v[2] + v[3];
  s[t] = sum4;
  __syncthreads();
  for (int off = 1; off < 256; off <<= 1) {
    unsigned add = (t >= off) ? s[t - off] : 0u;
    __syncthreads();
    s[t] += add;
    __syncthreads();
  }
  unsigned e = s[t] - sum4 + partial[blockIdx.x];
  for (int j = 0; j < 4; j++) {
    int i = base + j;
    if (i < n) {
      rowptr[i] = (int)e;
      if (i < NG) dis[i] = rsqrtf((float)v[j] + 1.0f);
      if (i == n - 1) rowptr[n] = (int)(e + v[j]);
      e += v[j];
    }
  }
}

// ---------------- pass B: place pairs into adj via LDS cursors (one block per bucket) ----------------
__global__ __launch_bounds__(256) void k_place(const int* __restrict__ rowptr,
                                               const uint2* __restrict__ pairs,
                                               int* __restrict__ adj) {
  __shared__ int cur[512];
  int b = blockIdx.x;
  int n0 = b << 9;
  int n1 = min(n0 + 512, NDOM);
  int t = threadIdx.x;
  for (int i = t; i < n1 - n0; i += 256) cur[i] = rowptr[n0 + i];
  __syncthreads();
  int cnt = rowptr[n1] - rowptr[n0];
  if (cnt > bcap(b)) cnt = bcap(b);
  const uint2* pb = pairs + bbase(b);
  for (int i = t; i < cnt; i += 256) {
    uint2 pr = pb[i];
    int p = atomicAdd(&cur[pr.x - (unsigned)n0], 1);
    adj[p] = (int)pr.y;
  }
}

// ---------------- prep: transpose weights to f16 [n][k] + watt ----------------
__global__ __launch_bounds__(256) void k_prep(const float* __restrict__ W1,
                                              const float* __restrict__ W2,
                                              const float* __restrict__ Wd,
                                              const float* __restrict__ Wc,
                                              const float* __restrict__ attd_d,
                                              const float* __restrict__ attd_c,
                                              __half* __restrict__ Wt1,
                                              __half* __restrict__ Wt2,
                                              __half* __restrict__ Wtd,
                                              __half* __restrict__ Wtc,
                                              float* __restrict__ watt) {
  int blk = blockIdx.x;
  if (blk == 10) {
    int t = threadIdx.x;
    for (int slot = t; slot < 1024; slot += 256) {
      int i = slot >> 3, s8 = slot & 7;
      const float* W = (s8 < 4) ? Wd : Wc;
      const float* A = (s8 < 4) ? attd_d : attd_c;
      int h = s8 & 3;
      float s = 0.f;
      for (int cc = 0; cc < 128; cc++) s += W[(size_t)i * 512 + h * 128 + cc] * A[h * 128 + cc];
      watt[i * 8 + s8] = s;
    }
    return;
  }
  const float* W;
  __half* Wt;
  int N, base;
  if (blk == 0) { W = W1; Wt = Wt1; N = 128; base = 0; }
  else if (blk == 1) { W = W2; Wt = Wt2; N = 128; base = 0; }
  else if (blk < 6) { W = Wd; Wt = Wtd; N = 512; base = (blk - 2) * 16384; }
  else { W = Wc; Wt = Wtc; N = 512; base = (blk - 6) * 16384; }
  for (int q = threadIdx.x; q < 16384; q += 256) {
    int qq = base + q;
    int n = qq >> 7, k = qq & 127;
    Wt[qq] = __float2half(W[(size_t)k * N + n]);
  }
}

// ---------------- MFMA f16 GEMM: hh[M,128] = (X[M,128] @ W) * dis[row], f16 out ----------------
template <int INF16>
__global__ __launch_bounds__(256) void k_mgemm(const void* __restrict__ Xv,
                                               const __half* __restrict__ Wt, int M,
                                               const float* __restrict__ dis,
                                               __half* __restrict__ hh) {
  __shared__ __align__(16) char lds[48 * 1024];
  char* As = lds;              // 64 x 128 f16 = 16 KB
  char* Bs = lds + 16 * 1024;  // 128 x 128 f16 = 32 KB
  const int t = threadIdx.x;
  const int row0 = blockIdx.x * 64;

#pragma unroll
  for (int rep = 0; rep < 8; rep++) {
    int q = t + rep * 256;
    int r = q >> 4, c16 = (q & 15) * 16;
    uint4 v = *(const uint4*)((const char*)Wt + r * 256 + c16);
    *(uint4*)(Bs + ((r * 256 + c16) ^ ((r & 7) << 4))) = v;
  }
  if (INF16 == 0) {
    const float* X = (const float*)Xv;
#pragma unroll
    for (int rep = 0; rep < 8; rep++) {
      int q = t + rep * 256;
      int r = q >> 5, c4 = (q & 31) * 4;
      int gr = row0 + r;
      float4 xv = make_float4(0.f, 0.f, 0.f, 0.f);
      if (gr < M) xv = *(const float4*)&X[(size_t)gr * 128 + c4];
      __half2 h0 = __floats2half2_rn(xv.x, xv.y);
      __half2 h1 = __floats2half2_rn(xv.z, xv.w);
      uint2 pk;
      pk.x = *(unsigned*)&h0;
      pk.y = *(unsigned*)&h1;
      *(uint2*)(As + ((r * 256 + c4 * 2) ^ ((r & 7) << 4))) = pk;
    }
  } else {
    const __half* X = (const __half*)Xv;
#pragma unroll
    for (int rep = 0; rep < 4; rep++) {
      int q = t + rep * 256;
      int r = q >> 4, c16 = (q & 15) * 16;
      int gr = row0 + r;
      uint4 v = make_uint4(0u, 0u, 0u, 0u);
      if (gr < M) v = *(const uint4*)((const char*)X + (size_t)gr * 256 + c16);
      *(uint4*)(As + ((r * 256 + c16) ^ ((r & 7) << 4))) = v;
    }
  }
  __syncthreads();

  const int w = t >> 6, l = t & 63;
  const int lr = l & 15, lk = l >> 4;
  f32x4 acc[8] = {};
#pragma unroll
  for (int s = 0; s < 4; s++) {
    int arow = w * 16 + lr;
    f16x8 a = *(const f16x8*)(As + ((arow * 256 + lk * 16 + s * 64) ^ ((arow & 7) << 4)));
#pragma unroll
    for (int nt = 0; nt < 8; nt++) {
      int brow = nt * 16 + lr;
      f16x8 b = *(const f16x8*)(Bs + ((brow * 256 + lk * 16 + s * 64) ^ ((brow & 7) << 4)));
      acc[nt] = __builtin_amdgcn_mfma_f32_16x16x32_f16(a, b, acc[nt], 0, 0, 0);
    }
  }
  float ddv[4];
  int rowb = row0 + w * 16 + lk * 4;
#pragma unroll
  for (int j = 0; j < 4; j++) ddv[j] = (rowb + j < M) ? dis[rowb + j] : 0.f;
#pragma unroll
  for (int nt = 0; nt < 8; nt++) {
#pragma unroll
    for (int j = 0; j < 4; j++) {
      int row = rowb + j;
      if (row < M) hh[(size_t)row * 128 + nt * 16 + lr] = __float2half(acc[nt][j] * ddv[j]);
    }
  }
}

// ---------------- MFMA f16 GAT GEMM (drug+disease in one launch) ----------------
__global__ __launch_bounds__(256) void k_mgat(const float* __restrict__ Xd,
                                              const float* __restrict__ Xc,
                                              const __half* __restrict__ Wtd,
                                              const __half* __restrict__ Wtc,
                                              const float* __restrict__ attSd,
                                              const float* __restrict__ attSc,
                                              __half* __restrict__ hsd,
                                              __half* __restrict__ hsc,
                                              float* __restrict__ a_s_d,
                                              float* __restrict__ a_s_c) {
  __shared__ __align__(16) char lds[48 * 1024];
  char* As = lds;
  char* Bs = lds + 16 * 1024;
  const int t = threadIdx.x;
  const int nbd = (NDR + 63) >> 6;
  const int q = blockIdx.x >= nbd;
  const int bx = q ? blockIdx.x - nbd : blockIdx.x;
  const int M = q ? NDI : NDR;
  const float* X = q ? Xc : Xd;
  const __half* Wt = q ? Wtc : Wtd;
  const float* attS = q ? attSc : attSd;
  __half* hs = q ? hsc : hsd;
  float* a_s = q ? a_s_c : a_s_d;
  const int row0 = bx * 64;
  const int h = blockIdx.y;
  const __half* Wth = Wt + (size_t)h * 128 * 128;

#pragma unroll
  for (int rep = 0; rep < 8; rep++) {
    int r = (t + rep * 256) >> 4, c16 = ((t + rep * 256) & 15) * 16;
    uint4 v = *(const uint4*)((const char*)Wth + r * 256 + c16);
    *(uint4*)(Bs + ((r * 256 + c16) ^ ((r & 7) << 4))) = v;
  }
#pragma unroll
  for (int rep = 0; rep < 8; rep++) {
    int qq = t + rep * 256;
    int r = qq >> 5, c4 = (qq & 31) * 4;
    int gr = row0 + r;
    float4 xv = make_float4(0.f, 0.f, 0.f, 0.f);
    if (gr < M) xv = *(const float4*)&X[(size_t)gr * 128 + c4];
    __half2 h0 = __floats2half2_rn(xv.x, xv.y);
    __half2 h1 = __floats2half2_rn(xv.z, xv.w);
    uint2 pk;
    pk.x = *(unsigned*)&h0;
    pk.y = *(unsigned*)&h1;
    *(uint2*)(As + ((r * 256 + c4 * 2) ^ ((r & 7) << 4))) = pk;
  }
  __syncthreads();

  const int w = t >> 6, l = t & 63;
  const int lr = l & 15, lk = l >> 4;
  f32x4 acc[8] = {};
#pragma unroll
  for (int s = 0; s < 4; s++) {
    int arow = w * 16 + lr;
    f16x8 a = *(const f16x8*)(As + ((arow * 256 + lk * 16 + s * 64) ^ ((arow & 7) << 4)));
#pragma unroll
    for (int nt = 0; nt < 8; nt++) {
      int brow = nt * 16 + lr;
      f16x8 b = *(const f16x8*)(Bs + ((brow * 256 + lk * 16 + s * 64) ^ ((brow & 7) << 4)));
      acc[nt] = __builtin_amdgcn_mfma_f32_16x16x32_f16(a, b, acc[nt], 0, 0, 0);
    }
  }
  float av[8];
#pragma unroll
  for (int nt = 0; nt < 8; nt++) av[nt] = attS[h * 128 + nt * 16 + lr];

  int rowb = row0 + w * 16 + lk * 4;
  float p[4] = {0.f, 0.f, 0.f, 0.f};
#pragma unroll
  for (int nt = 0; nt < 8; nt++) {
#pragma unroll
    for (int j = 0; j < 4; j++) {
      int row = rowb + j;
      if (row < M) hs[(size_t)row * 512 + h * 128 + nt * 16 + lr] = __float2half(acc[nt][j]);
      p[j] += acc[nt][j] * av[nt];
    }
  }
#pragma unroll
  for (int m = 1; m < 16; m <<= 1) {
#pragma unroll
    for (int j = 0; j < 4; j++) p[j] += __shfl_xor(p[j], m);
  }
  if (lr == 0) {
#pragma unroll
    for (int j = 0; j < 4; j++) {
      int row = rowb + j;
      if (row < M) a_s[(size_t)row * 4 + h] = p[j];
    }
  }
}

// ---------------- GCN aggregation: wave/dst, 2 lane-groups x 32 lanes, ILP-4/group ----------------
// FIN 1: out = x1 row f16; FIN 2: out = att row (8 scores fp32)
template <int FIN>
__global__ __launch_bounds__(256) void k_gather(const __half* __restrict__ hh,
                                                const int* __restrict__ rowptr,
                                                const int* __restrict__ adj,
                                                const float* __restrict__ dis,
                                                const float* __restrict__ b,
                                                const float* __restrict__ watt,
                                                void* __restrict__ outv, int n) {
  int wid = threadIdx.x >> 6;
  int lane = threadIdx.x & 63;
  int g = lane >> 5;   // 0/1 — neighbor-list split
  int sl = lane & 31;  // column group: 4 halfs each
  int d = blockIdx.x * 4 + wid;
  if (d >= n) return;
  int p0 = rowptr[d], p1 = rowptr[d + 1];
  int c = sl * 4;
  float acc0 = 0.f, acc1 = 0.f, acc2 = 0.f, acc3 = 0.f;
  if (g == 0) {  // self loop
    uint2 v = *(const uint2*)&hh[(size_t)d * 128 + c];
    float2 f0 = __half22float2(*(__half2*)&v.x);
    float2 f1 = __half22float2(*(__half2*)&v.y);
    acc0 = f0.x; acc1 = f0.y; acc2 = f1.x; acc3 = f1.y;
  }
  for (int base = p0; base < p1; base += 64) {
    int remain = p1 - base;
    int m = remain < 64 ? remain : 64;
    int idx = (lane < m) ? adj[base + lane] : 0;
    int j = g;
    for (; j + 6 < m; j += 8) {
      int nb0 = __shfl(idx, j);
      int nb1 = __shfl(idx, j + 2);
      int nb2 = __shfl(idx, j + 4);
      int nb3 = __shfl(idx, j + 6);
      uint2 v0 = *(const uint2*)&hh[(size_t)nb0 * 128 + c];
      uint2 v1 = *(const uint2*)&hh[(size_t)nb1 * 128 + c];
      uint2 v2 = *(const uint2*)&hh[(size_t)nb2 * 128 + c];
      uint2 v3 = *(const uint2*)&hh[(size_t)nb3 * 128 + c];
      float2 a0 = __half22float2(*(__half2*)&v0.x), b0 = __half22float2(*(__half2*)&v0.y);
      float2 a1 = __half22float2(*(__half2*)&v1.x), b1 = __half22float2(*(__half2*)&v1.y);
      float2 a2 = __half22float2(*(__half2*)&v2.x), b2 = __half22float2(*(__half2*)&v2.y);
      float2 a3 = __half22float2(*(__half2*)&v3.x), b3 = __half22float2(*(__half2*)&v3.y);
      acc0 += (a0.x + a1.x) + (a2.x + a3.x);
      acc1 += (a0.y + a1.y) + (a2.y + a3.y);
      acc2 += (b0.x + b1.x) + (b2.x + b3.x);
      acc3 += (b0.y + b1.y) + (b2.y + b3.y);
    }
    for (; j < m; j += 2) {
      int nb = __shfl(idx, j);
      uint2 v = *(const uint2*)&hh[(size_t)nb * 128 + c];
      float2 f0 = __half22float2(*(__half2*)&v.x);
      float2 f1 = __half22float2(*(__half2*)&v.y);
      acc0 += f0.x; acc1 += f0.y; acc2 += f1.x; acc3 += f1.y;
    }
  }
  // combine the two neighbor-split groups
  acc0 += __shfl_xor(acc0, 32);
  acc1 += __shfl_xor(acc1, 32);
  acc2 += __shfl_xor(acc2, 32);
  acc3 += __shfl_xor(acc3, 32);
  float dd = dis[d];
  float x0 = fmaxf(dd * acc0 + b[c], 0.f);
  float x1 = fmaxf(dd * acc1 + b[c + 1], 0.f);
  float x2 = fmaxf(dd * acc2 + b[c + 2], 0.f);
  float x3 = fmaxf(dd * acc3 + b[c + 3], 0.f);
  if (FIN == 1) {
    if (g == 0) {
      __half2 h01 = __floats2half2_rn(x0, x1);
      __half2 h23 = __floats2half2_rn(x2, x3);
      uint2 pk;
      pk.x = *(unsigned*)&h01;
      pk.y = *(unsigned*)&h23;
      *(uint2*)&((__half*)outv)[(size_t)d * 128 + c] = pk;
    }
  } else {
    float p[8];
    const float* w0 = &watt[c * 8];
#pragma unroll
    for (int h = 0; h < 8; h++)
      p[h] = x0 * w0[h] + x1 * w0[8 + h] + x2 * w0[16 + h] + x3 * w0[24 + h];
#pragma unroll
    for (int mm = 1; mm < 32; mm <<= 1) {
#pragma unroll
      for (int h = 0; h < 8; h++) p[h] += __shfl_xor(p[h], mm);
    }
    if (lane == 0) {
      float* o = (float*)outv;
      *(float4*)&o[(size_t)d * 8] = make_float4(p[0], p[1], p[2], p[3]);
      *(float4*)&o[(size_t)d * 8 + 4] = make_float4(p[4], p[5], p[6], p[7]);
    }
  }
}

// ---------------- GAT softmax pass A: denom by dst-gather (regions at NG, 2NG) ----------------
__global__ __launch_bounds__(256) void k_edgeA(const int* __restrict__ rowptr,
                                               const int* __restrict__ adj,
                                               const float* __restrict__ a_s_d,
                                               const float* __restrict__ a_s_c,
                                               const float* __restrict__ att,
                                               float* __restrict__ denom_d,
                                               float* __restrict__ denom_c) {
  int nb1 = (NG + 255) >> 8;
  int blk = blockIdx.x;
  int q = blk >= nb1;
  int d = (blk - (q ? nb1 : 0)) * 256 + threadIdx.x;
  if (d >= NG) return;
  const int* rp = rowptr + NG + (q ? NG : 0);
  const float* a_s = q ? a_s_c : a_s_d;
  float* den = q ? denom_c : denom_d;
  int p0 = rp[d], p1 = rp[d + 1];
  float4 ad4 = *(const float4*)&att[(size_t)d * 8 + q * 4];
  float4 acc = make_float4(0.f, 0.f, 0.f, 0.f);
  for (int p = p0; p < p1; p++) {
    int s = adj[p];
    float4 as4 = *(const float4*)&a_s[(size_t)s * 4];
    float v0 = as4.x + ad4.x, v1 = as4.y + ad4.y, v2 = as4.z + ad4.z, v3 = as4.w + ad4.w;
    v0 = v0 > 0.f ? v0 : 0.2f * v0;
    v1 = v1 > 0.f ? v1 : 0.2f * v1;
    v2 = v2 > 0.f ? v2 : 0.2f * v2;
    v3 = v3 > 0.f ? v3 : 0.2f * v3;
    acc.x += __expf(fminf(v0, 50.f));
    acc.y += __expf(fminf(v1, 50.f));
    acc.z += __expf(fminf(v2, 50.f));
    acc.w += __expf(fminf(v3, 50.f));
  }
  *(float4*)&den[(size_t)d * 4] = acc;
}

// ---------------- GAT softmax pass B: wsrc by src-gather (regions at 3NG, 3NG+NDR) ----------------
__global__ __launch_bounds__(256) void k_edgeB(const int* __restrict__ rowptr,
                                               const int* __restrict__ adj,
                                               const float* __restrict__ a_s_d,
                                               const float* __restrict__ a_s_c,
                                               const float* __restrict__ att,
                                               const float* __restrict__ denom_d,
                                               const float* __restrict__ denom_c,
                                               float* __restrict__ wsrc_d,
                                               float* __restrict__ wsrc_c) {
  int gw = (blockIdx.x * 256 + threadIdx.x) >> 6;
  int lane = threadIdx.x & 63;
  int q = gw >= NDR;
  int s = q ? gw - NDR : gw;
  if (q && s >= NDI) return;
  const int* rp = rowptr + 3 * NG + (q ? NDR : 0);
  const float* a_s = q ? a_s_c : a_s_d;
  const float* den = q ? denom_c : denom_d;
  float* ws = q ? wsrc_c : wsrc_d;
  int p0 = rp[s], p1 = rp[s + 1];
  float4 as4 = *(const float4*)&a_s[(size_t)s * 4];
  int attoff = q * 4;
  float4 acc = make_float4(0.f, 0.f, 0.f, 0.f);
  for (int p = p0 + lane; p < p1; p += 64) {
    int d = adj[p];
    float4 ad4 = *(const float4*)&att[(size_t)d * 8 + attoff];
    float4 dn = *(const float4*)&den[(size_t)d * 4];
    float v0 = as4.x + ad4.x, v1 = as4.y + ad4.y, v2 = as4.z + ad4.z, v3 = as4.w + ad4.w;
    v0 = v0 > 0.f ? v0 : 0.2f * v0;
    v1 = v1 > 0.f ? v1 : 0.2f * v1;
    v2 = v2 > 0.f ? v2 : 0.2f * v2;
    v3 = v3 > 0.f ? v3 : 0.2f * v3;
    acc.x += __expf(fminf(v0, 50.f)) / (dn.x + 1e-16f);
    acc.y += __expf(fminf(v1, 50.f)) / (dn.y + 1e-16f);
    acc.z += __expf(fminf(v2, 50.f)) / (dn.z + 1e-16f);
    acc.w += __expf(fminf(v3, 50.f)) / (dn.w + 1e-16f);
  }
#pragma unroll
  for (int m = 1; m < 64; m <<= 1) {
    acc.x += __shfl_xor(acc.x, m);
    acc.y += __shfl_xor(acc.y, m);
    acc.z += __shfl_xor(acc.z, m);
    acc.w += __shfl_xor(acc.w, m);
  }
  if (lane == 0) *(float4*)&ws[(size_t)s * 4] = acc;
}

// ---------------- fused weighted column sums + embedding column sums ----------------
__global__ __launch_bounds__(512) void k_sum(const __half* __restrict__ hs_d,
                                             const float* __restrict__ wsrc_d,
                                             float* __restrict__ S_d,
                                             const __half* __restrict__ hs_c,
                                             const float* __restrict__ wsrc_c,
                                             float* __restrict__ S_c,
                                             const float* __restrict__ xd,
                                             float* __restrict__ od,
                                             const float* __restrict__ xc,
                                             float* __restrict__ oc) {
  int t = threadIdx.x;
  const int nws_d = (NDR + 63) >> 6;
  const int nws_c = (NDI + 63) >> 6;
  const int ncs_d = (NDR + 511) >> 9;
  int blk = blockIdx.x;
  if (blk < nws_d + nws_c) {
    int q = blk >= nws_d;
    const __half* hs = q ? hs_c : hs_d;
    const float* wsrc = q ? wsrc_c : wsrc_d;
    float* S = q ? S_c : S_d;
    int N = q ? NDI : NDR;
    int r0 = (q ? blk - nws_d : blk) * 64;
    int h = t >> 7;
    int r1 = min(r0 + 64, N);
    float acc = 0.f;
    for (int r = r0; r < r1; r++) acc += wsrc[r * 4 + h] * __half2float(hs[(size_t)r * 512 + t]);
    atomAddF(&S[t], acc);
  } else {
    int cb = blk - nws_d - nws_c;
    int q = cb >= ncs_d;
    const float* x = q ? xc : xd;
    float* o = q ? oc : od;
    int N = q ? NDI : NDR;
    int r0 = (q ? cb - ncs_d : cb) * 512 + (t >> 7) * 128;
    int col = t & 127;
    int r1 = min(r0 + 128, N);
    float acc = 0.f;
    for (int r = r0; r < r1; r++) acc += x[(size_t)r * 128 + col];
    if (r0 < N) atomAddF(&o[col], acc);
  }
}

// ---------------- final fuse ----------------
__global__ __launch_bounds__(128) void k_final(const float* __restrict__ S_d,
                                               const float* __restrict__ S_c,
                                               const float* __restrict__ bdsum,
                                               const float* __restrict__ bcsum,
                                               const float* __restrict__ bd_bias,
                                               const float* __restrict__ bc_bias,
                                               const float* __restrict__ fuse_w,
                                               const float* __restrict__ fuse_b,
                                               float* __restrict__ out) {
  __shared__ float cat[384];
  int t = threadIdx.x;
  float sd = S_d[t] + S_d[128 + t] + S_d[256 + t] + S_d[384 + t];
  float sc = S_c[t] + S_c[128 + t] + S_c[256 + t] + S_c[384 + t];
  const float inv = 1.0f / (4.0f * (float)NG);
  cat[t] = 0.5f * (sd * inv + bd_bias[t] + sc * inv + bc_bias[t]);
  cat[128 + t] = bdsum[t] * (1.0f / (float)NDR);
  cat[256 + t] = bcsum[t] * (1.0f / (float)NDI);
  __syncthreads();
  float o = fuse_b[t];
  for (int k = 0; k < 384; k++) o += cat[k] * fuse_w[k * 128 + t];
  out[t] = o;
}

// ---------------- host launch ----------------
extern "C" void kernel_launch(void* const* d_in, const int* in_sizes, int n_in,
                              void* d_out, int out_size, void* d_ws, size_t ws_size,
                              hipStream_t stream) {
  const float* gene_nodes   = (const float*)d_in[0];
  const int*   drug_edges   = (const int*)d_in[1];
  const int*   dise_edges   = (const int*)d_in[2];
  const int*   gene_edges   = (const int*)d_in[3];
  const float* gcn1_w       = (const float*)d_in[4];
  const float* gcn1_b       = (const float*)d_in[5];
  const float* gcn2_w       = (const float*)d_in[6];
  const float* gcn2_b       = (const float*)d_in[7];
  const float* drug_embed   = (const float*)d_in[8];
  const float* dise_embed   = (const float*)d_in[9];
  const float* gat_d_w      = (const float*)d_in[10];
  const float* gat_d_att_s  = (const float*)d_in[11];
  const float* gat_d_att_d  = (const float*)d_in[12];
  const float* gat_d_b      = (const float*)d_in[13];
  const float* gat_c_w      = (const float*)d_in[14];
  const float* gat_c_att_s  = (const float*)d_in[15];
  const float* gat_c_att_d  = (const float*)d_in[16];
  const float* gat_c_b      = (const float*)d_in[17];
  const float* fuse_w       = (const float*)d_in[18];
  const float* fuse_b       = (const float*)d_in[19];
  const int Ed = in_sizes[1] / 2;
  const int Ec = in_sizes[2] / 2;
  const int Eg = in_sizes[3] / 2;
  float* out = (float*)d_out;
  (void)n_in; (void)out_size; (void)ws_size;

  const int NBS = cdiv_h(NDOM, 1024);                                 // 308 scan blocks
  const size_t NPAIR = (size_t)NBSMALL * CAP_S + 30 * (size_t)CAP_L;  // pair buffer capacity

  // workspace layout (zero-init region first, single memset)
  char* w = (char*)d_ws;
  auto alloc = [&](size_t n) {
    char* p = w;
    w += (n + 511) & ~(size_t)511;
    return p;
  };
  char* z0 = w;
  unsigned* deg     = (unsigned*)alloc((size_t)NDOM * 4);
  int* bcur         = (int*)alloc((size_t)NBUCK * 4);
  float* S_d        = (float*)alloc(512 * 4);
  float* S_c        = (float*)alloc(512 * 4);
  float* bdsum      = (float*)alloc(512);
  float* bcsum      = (float*)alloc(512);
  size_t zbytes = (size_t)(w - z0);
  float* denom_d    = (float*)alloc((size_t)NG * 16);
  float* denom_c    = (float*)alloc((size_t)NG * 16);
  float* wsrc_d     = (float*)alloc((size_t)NDR * 16);
  float* wsrc_c     = (float*)alloc((size_t)NDI * 16);
  float* dis        = (float*)alloc((size_t)NG * 4);
  float* watt       = (float*)alloc(128 * 8 * 4);
  float* att        = (float*)alloc((size_t)NG * 8 * 4);
  float* a_s_d      = (float*)alloc((size_t)NDR * 16);
  float* a_s_c      = (float*)alloc((size_t)NDI * 16);
  unsigned* partial = (unsigned*)alloc((size_t)512 * 4);
  int* rowptr       = (int*)alloc((size_t)(NDOM + 1) * 4);
  int* adj          = (int*)alloc((size_t)(Eg + 2 * (Ed + Ec)) * 4);
  uint2* pairs      = (uint2*)alloc(NPAIR * 8);
  __half* Wt1       = (__half*)alloc((size_t)128 * 128 * 2);
  __half* Wt2       = (__half*)alloc((size_t)128 * 128 * 2);
  __half* Wtd       = (__half*)alloc((size_t)512 * 128 * 2);
  __half* Wtc       = (__half*)alloc((size_t)512 * 128 * 2);
  __half* hh        = (__half*)alloc((size_t)NG * 128 * 2);
  __half* x1        = (__half*)alloc((size_t)NG * 128 * 2);
  __half* hs_d      = (__half*)alloc((size_t)NDR * 512 * 2);
  __half* hs_c      = (__half*)alloc((size_t)NDI * 512 * 2);

  hipMemsetAsync(z0, 0, zbytes, stream);

  // CSR build: bin(+deg) -> scan -> rowptr -> place
  int nbe = cdiv_h(Eg, 256) + cdiv_h(Ed, 256) + cdiv_h(Ec, 256);
  k_binA<<<nbe, 256, 0, stream>>>(gene_edges, Eg, drug_edges, Ed, dise_edges, Ec,
                                  deg, bcur, pairs);
  k_blocksum4<<<NBS, 256, 0, stream>>>(deg, partial, NDOM);
  k_scanpart<<<1, 512, 0, stream>>>(partial, NBS);
  k_rowptrAll<<<NBS, 256, 0, stream>>>(deg, partial, NDOM, rowptr, dis);
  k_place<<<NBUCK, 256, 0, stream>>>(rowptr, pairs, adj);
  k_prep<<<11, 256, 0, stream>>>(gcn1_w, gcn2_w, gat_d_w, gat_c_w, gat_d_att_d, gat_c_att_d,
                                 Wt1, Wt2, Wtd, Wtc, watt);

  // GCN layer 1
  k_mgemm<0><<<cdiv_h(NG, 64), 256, 0, stream>>>(gene_nodes, Wt1, NG, dis, hh);
  k_gather<1><<<cdiv_h(NG, 4), 256, 0, stream>>>(hh, rowptr, adj, dis, gcn1_b, nullptr, x1, NG);

  // GCN layer 2 (f16 input; att-score epilogue; x2 never materialized)
  k_mgemm<1><<<cdiv_h(NG, 64), 256, 0, stream>>>(x1, Wt2, NG, dis, hh);
  k_gather<2><<<cdiv_h(NG, 4), 256, 0, stream>>>(hh, rowptr, adj, dis, gcn2_b, watt, att, NG);

  // GAT source transforms (both graphs, one launch)
  k_mgat<<<dim3(cdiv_h(NDR, 64) + cdiv_h(NDI, 64), 4), 256, 0, stream>>>(
      drug_embed, dise_embed, Wtd, Wtc, gat_d_att_s, gat_c_att_s, hs_d, hs_c, a_s_d, a_s_c);

  // GAT softmax: denom by dst-gather, wsrc by src-gather (no atomics)
  k_edgeA<<<2 * cdiv_h(NG, 256), 256, 0, stream>>>(rowptr, adj, a_s_d, a_s_c, att, denom_d, denom_c);
  k_edgeB<<<cdiv_h((NDR + NDI) * 64, 256), 256, 0, stream>>>(rowptr, adj, a_s_d, a_s_c, att,
                                                             denom_d, denom_c, wsrc_d, wsrc_c);

  // fused weighted column sums + embedding means
  int nsum = (cdiv_h(NDR, 64) + cdiv_h(NDI, 64)) + (cdiv_h(NDR, 512) + cdiv_h(NDI, 512));
  k_sum<<<nsum, 512, 0, stream>>>(hs_d, wsrc_d, S_d, hs_c, wsrc_c, S_c,
                                  drug_embed, bdsum, dise_embed, bcsum);

  // final fuse
  k_final<<<1, 128, 0, stream>>>(S_d, S_c, bdsum, bcsum, gat_d_b, gat_c_b, fuse_w, fuse_b, out);
}

// Round 9
// 545.804 us; speedup vs baseline: 3.8341x; 3.8341x over previous
//
#include <hip/hip_runtime.h>
#include <hip/hip_fp16.h>

#define NG 100000
#define NDR 10000
#define NDI 5000
#define NDOM (3 * NG + NDR + NDI)   // 315000 combined node domain
#define SL 39375                    // NDOM / 8 node-range slice (exact)

typedef _Float16 f16x8 __attribute__((ext_vector_type(8)));
typedef float f32x4 __attribute__((ext_vector_type(4)));

__device__ __forceinline__ void atomAddF(float* p, float v) { unsafeAtomicAdd(p, v); }

static inline int cdiv_h(int a, int b) { return (a + b - 1) / b; }

// ---------------- XCD-sliced CSR build: PASS 0 = degree count, PASS 1 = cursor fill ----------------
// blockIdx&7 selects a node-range slice; under round-robin block->XCD dispatch each slice's
// atomics+writes stay in one XCD's L2 (1MB adj slice), eliminating cross-XCD line thrash.
// Each slice-group rescans all edges (L3-resident). Correct for ANY block->XCD mapping.
template <int PASS>
__global__ __launch_bounds__(256) void k_build(const int* __restrict__ ge, int Eg_,
                                               const int* __restrict__ de, int Ed_,
                                               const int* __restrict__ ce, int Ec_,
                                               unsigned* __restrict__ deg,
                                               int* __restrict__ cursor,
                                               int* __restrict__ adj) {
  const unsigned slice = blockIdx.x & 7;
  const int chunk = blockIdx.x >> 3;
  const unsigned lo = slice * SL;
  const int nb_g = (Eg_ + 1023) >> 10, nb_d = (Ed_ + 1023) >> 10;
  const int* src;
  const int* dst;
  int E, cb, mode;
  unsigned offD = 0, offS = 0;
  if (chunk < nb_g) {
    src = ge; dst = ge + Eg_; E = Eg_; cb = chunk; mode = 0;
  } else if (chunk < nb_g + nb_d) {
    src = de; dst = de + Ed_; E = Ed_; cb = chunk - nb_g; mode = 1;
    offD = NG; offS = 3 * NG;
  } else {
    src = ce; dst = ce + Ec_; E = Ec_; cb = chunk - nb_g - nb_d; mode = 2;
    offD = 2 * NG; offS = 3 * NG + NDR;
  }
  int e0 = (cb << 10) + (int)threadIdx.x * 4;
  if (e0 >= E) return;
  int4 s4, d4;
  if (e0 + 3 < E) {
    s4 = *(const int4*)&src[e0];
    d4 = *(const int4*)&dst[e0];
  } else {
    int* sp = (int*)&s4;
    int* dp = (int*)&d4;
    for (int j = 0; j < 4; j++) {
      sp[j] = (e0 + j < E) ? src[e0 + j] : 0;
      dp[j] = (e0 + j < E) ? dst[e0 + j] : 0;
    }
  }
  const int* sp = (const int*)&s4;
  const int* dp = (const int*)&d4;
#pragma unroll
  for (int j = 0; j < 4; j++) {
    if (e0 + j >= E) break;
    unsigned nd = offD + (unsigned)dp[j];
    if (nd - lo < SL) {
      if (PASS == 0) {
        atomicAdd(&deg[nd], 1u);
      } else {
        int p = atomicAdd(&cursor[nd], 1);
        adj[p] = sp[j];
      }
    }
    if (mode != 0) {
      unsigned ns = offS + (unsigned)sp[j];
      if (ns - lo < SL) {
        if (PASS == 0) {
          atomicAdd(&deg[ns], 1u);
        } else {
          int p = atomicAdd(&cursor[ns], 1);
          adj[p] = dp[j];
        }
      }
    }
  }
}

// ---------------- scan (1024 elems/block) ----------------
__global__ __launch_bounds__(256) void k_blocksum4(const unsigned* __restrict__ deg,
                                                   unsigned* __restrict__ partial, int n) {
  __shared__ unsigned s[256];
  int t = threadIdx.x;
  int base = blockIdx.x * 1024 + t * 4;
  unsigned v = 0;
  if (base + 3 < n) {
    uint4 u = *(const uint4*)&deg[base];
    v = u.x + u.y + u.z + u.w;
  } else {
    for (int j = 0; j < 4; j++)
      if (base + j < n) v += deg[base + j];
  }
  s[t] = v;
  __syncthreads();
  for (int off = 128; off; off >>= 1) {
    if (t < off) s[t] += s[t + off];
    __syncthreads();
  }
  if (!t) partial[blockIdx.x] = s[0];
}

__global__ __launch_bounds__(512) void k_scanpart(unsigned* __restrict__ partial, int nb) {
  __shared__ unsigned s[512];
  int t = threadIdx.x;
  unsigned v = (t < nb) ? partial[t] : 0u;
  s[t] = v;
  __syncthreads();
  for (int off = 1; off < 512; off <<= 1) {
    unsigned add = (t >= off) ? s[t - off] : 0u;
    __syncthreads();
    s[t] += add;
    __syncthreads();
  }
  if (t < nb) partial[t] = s[t] - v;  // exclusive
}

__global__ __launch_bounds__(256) void k_rowptrAll(const unsigned* __restrict__ deg,
                                                   const unsigned* __restrict__ partial, int n,
                                                   int* __restrict__ rowptr,
                                                   int* __restrict__ cursor,
                                                   float* __restrict__ dis) {
  __shared__ unsigned s[256];
  int t = threadIdx.x;
  int base = blockIdx.x * 1024 + t * 4;
  unsigned v[4] = {0u, 0u, 0u, 0u};
  if (base + 3 < n) {
    uint4 u = *(const uint4*)&deg[base];
    v[0] = u.x; v[1] = u.y; v[2] = u.z; v[3] = u.w;
  } else {
    for (int j = 0; j < 4; j++)
      if (base + j < n) v[j] = deg[base + j];
  }
  unsigned sum4 = v[0] + v[1] + v[2] + v[3];
  s[t] = sum4;
  __syncthreads();
  for (int off = 1; off < 256; off <<= 1) {
    unsigned add = (t >= off) ? s[t - off] : 0u;
    __syncthreads();
    s[t] += add;
    __syncthreads();
  }
  unsigned e = s[t] - sum4 + partial[blockIdx.x];
  for (int j = 0; j < 4; j++) {
    int i = base + j;
    if (i < n) {
      rowptr[i] = (int)e;
      cursor[i] = (int)e;
      if (i < NG) dis[i] = rsqrtf((float)v[j] + 1.0f);
      if (i == n - 1) rowptr[n] = (int)(e + v[j]);
      e += v[j];
    }
  }
}

// ---------------- prep: transpose weights to f16 [n][k] + watt ----------------
__global__ __launch_bounds__(256) void k_prep(const float* __restrict__ W1,
                                              const float* __restrict__ W2,
                                              const float* __restrict__ Wd,
                                              const float* __restrict__ Wc,
                                              const float* __restrict__ attd_d,
                                              const float* __restrict__ attd_c,
                                              __half* __restrict__ Wt1,
                                              __half* __restrict__ Wt2,
                                              __half* __restrict__ Wtd,
                                              __half* __restrict__ Wtc,
                                              float* __restrict__ watt) {
  int blk = blockIdx.x;
  if (blk == 10) {
    int t = threadIdx.x;
    for (int slot = t; slot < 1024; slot += 256) {
      int i = slot >> 3, s8 = slot & 7;
      const float* W = (s8 < 4) ? Wd : Wc;
      const float* A = (s8 < 4) ? attd_d : attd_c;
      int h = s8 & 3;
      float s = 0.f;
      for (int cc = 0; cc < 128; cc++) s += W[(size_t)i * 512 + h * 128 + cc] * A[h * 128 + cc];
      watt[i * 8 + s8] = s;
    }
    return;
  }
  const float* W;
  __half* Wt;
  int N, base;
  if (blk == 0) { W = W1; Wt = Wt1; N = 128; base = 0; }
  else if (blk == 1) { W = W2; Wt = Wt2; N = 128; base = 0; }
  else if (blk < 6) { W = Wd; Wt = Wtd; N = 512; base = (blk - 2) * 16384; }
  else { W = Wc; Wt = Wtc; N = 512; base = (blk - 6) * 16384; }
  for (int q = threadIdx.x; q < 16384; q += 256) {
    int qq = base + q;
    int n = qq >> 7, k = qq & 127;
    Wt[qq] = __float2half(W[(size_t)k * N + n]);
  }
}

// ---------------- MFMA f16 GEMM: hh[M,128] = (X[M,128] @ W) * dis[row], f16 out ----------------
template <int INF16>
__global__ __launch_bounds__(256) void k_mgemm(const void* __restrict__ Xv,
                                               const __half* __restrict__ Wt, int M,
                                               const float* __restrict__ dis,
                                               __half* __restrict__ hh) {
  __shared__ __align__(16) char lds[48 * 1024];
  char* As = lds;              // 64 x 128 f16 = 16 KB
  char* Bs = lds + 16 * 1024;  // 128 x 128 f16 = 32 KB
  const int t = threadIdx.x;
  const int row0 = blockIdx.x * 64;

#pragma unroll
  for (int rep = 0; rep < 8; rep++) {
    int q = t + rep * 256;
    int r = q >> 4, c16 = (q & 15) * 16;
    uint4 v = *(const uint4*)((const char*)Wt + r * 256 + c16);
    *(uint4*)(Bs + ((r * 256 + c16) ^ ((r & 7) << 4))) = v;
  }
  if (INF16 == 0) {
    const float* X = (const float*)Xv;
#pragma unroll
    for (int rep = 0; rep < 8; rep++) {
      int q = t + rep * 256;
      int r = q >> 5, c4 = (q & 31) * 4;
      int gr = row0 + r;
      float4 xv = make_float4(0.f, 0.f, 0.f, 0.f);
      if (gr < M) xv = *(const float4*)&X[(size_t)gr * 128 + c4];
      __half2 h0 = __floats2half2_rn(xv.x, xv.y);
      __half2 h1 = __floats2half2_rn(xv.z, xv.w);
      uint2 pk;
      pk.x = *(unsigned*)&h0;
      pk.y = *(unsigned*)&h1;
      *(uint2*)(As + ((r * 256 + c4 * 2) ^ ((r & 7) << 4))) = pk;
    }
  } else {
    const __half* X = (const __half*)Xv;
#pragma unroll
    for (int rep = 0; rep < 4; rep++) {
      int q = t + rep * 256;
      int r = q >> 4, c16 = (q & 15) * 16;
      int gr = row0 + r;
      uint4 v = make_uint4(0u, 0u, 0u, 0u);
      if (gr < M) v = *(const uint4*)((const char*)X + (size_t)gr * 256 + c16);
      *(uint4*)(As + ((r * 256 + c16) ^ ((r & 7) << 4))) = v;
    }
  }
  __syncthreads();

  const int w = t >> 6, l = t & 63;
  const int lr = l & 15, lk = l >> 4;
  f32x4 acc[8] = {};
#pragma unroll
  for (int s = 0; s < 4; s++) {
    int arow = w * 16 + lr;
    f16x8 a = *(const f16x8*)(As + ((arow * 256 + lk * 16 + s * 64) ^ ((arow & 7) << 4)));
#pragma unroll
    for (int nt = 0; nt < 8; nt++) {
      int brow = nt * 16 + lr;
      f16x8 b = *(const f16x8*)(Bs + ((brow * 256 + lk * 16 + s * 64) ^ ((brow & 7) << 4)));
      acc[nt] = __builtin_amdgcn_mfma_f32_16x16x32_f16(a, b, acc[nt], 0, 0, 0);
    }
  }
  float ddv[4];
  int rowb = row0 + w * 16 + lk * 4;
#pragma unroll
  for (int j = 0; j < 4; j++) ddv[j] = (rowb + j < M) ? dis[rowb + j] : 0.f;
#pragma unroll
  for (int nt = 0; nt < 8; nt++) {
#pragma unroll
    for (int j = 0; j < 4; j++) {
      int row = rowb + j;
      if (row < M) hh[(size_t)row * 128 + nt * 16 + lr] = __float2half(acc[nt][j] * ddv[j]);
    }
  }
}

// ---------------- MFMA f16 GAT GEMM (drug+disease in one launch) ----------------
__global__ __launch_bounds__(256) void k_mgat(const float* __restrict__ Xd,
                                              const float* __restrict__ Xc,
                                              const __half* __restrict__ Wtd,
                                              const __half* __restrict__ Wtc,
                                              const float* __restrict__ attSd,
                                              const float* __restrict__ attSc,
                                              __half* __restrict__ hsd,
                                              __half* __restrict__ hsc,
                                              float* __restrict__ a_s_d,
                                              float* __restrict__ a_s_c) {
  __shared__ __align__(16) char lds[48 * 1024];
  char* As = lds;
  char* Bs = lds + 16 * 1024;
  const int t = threadIdx.x;
  const int nbd = (NDR + 63) >> 6;
  const int q = blockIdx.x >= nbd;
  const int bx = q ? blockIdx.x - nbd : blockIdx.x;
  const int M = q ? NDI : NDR;
  const float* X = q ? Xc : Xd;
  const __half* Wt = q ? Wtc : Wtd;
  const float* attS = q ? attSc : attSd;
  __half* hs = q ? hsc : hsd;
  float* a_s = q ? a_s_c : a_s_d;
  const int row0 = bx * 64;
  const int h = blockIdx.y;
  const __half* Wth = Wt + (size_t)h * 128 * 128;

#pragma unroll
  for (int rep = 0; rep < 8; rep++) {
    int r = (t + rep * 256) >> 4, c16 = ((t + rep * 256) & 15) * 16;
    uint4 v = *(const uint4*)((const char*)Wth + r * 256 + c16);
    *(uint4*)(Bs + ((r * 256 + c16) ^ ((r & 7) << 4))) = v;
  }
#pragma unroll
  for (int rep = 0; rep < 8; rep++) {
    int qq = t + rep * 256;
    int r = qq >> 5, c4 = (qq & 31) * 4;
    int gr = row0 + r;
    float4 xv = make_float4(0.f, 0.f, 0.f, 0.f);
    if (gr < M) xv = *(const float4*)&X[(size_t)gr * 128 + c4];
    __half2 h0 = __floats2half2_rn(xv.x, xv.y);
    __half2 h1 = __floats2half2_rn(xv.z, xv.w);
    uint2 pk;
    pk.x = *(unsigned*)&h0;
    pk.y = *(unsigned*)&h1;
    *(uint2*)(As + ((r * 256 + c4 * 2) ^ ((r & 7) << 4))) = pk;
  }
  __syncthreads();

  const int w = t >> 6, l = t & 63;
  const int lr = l & 15, lk = l >> 4;
  f32x4 acc[8] = {};
#pragma unroll
  for (int s = 0; s < 4; s++) {
    int arow = w * 16 + lr;
    f16x8 a = *(const f16x8*)(As + ((arow * 256 + lk * 16 + s * 64) ^ ((arow & 7) << 4)));
#pragma unroll
    for (int nt = 0; nt < 8; nt++) {
      int brow = nt * 16 + lr;
      f16x8 b = *(const f16x8*)(Bs + ((brow * 256 + lk * 16 + s * 64) ^ ((brow & 7) << 4)));
      acc[nt] = __builtin_amdgcn_mfma_f32_16x16x32_f16(a, b, acc[nt], 0, 0, 0);
    }
  }
  float av[8];
#pragma unroll
  for (int nt = 0; nt < 8; nt++) av[nt] = attS[h * 128 + nt * 16 + lr];

  int rowb = row0 + w * 16 + lk * 4;
  float p[4] = {0.f, 0.f, 0.f, 0.f};
#pragma unroll
  for (int nt = 0; nt < 8; nt++) {
#pragma unroll
    for (int j = 0; j < 4; j++) {
      int row = rowb + j;
      if (row < M) hs[(size_t)row * 512 + h * 128 + nt * 16 + lr] = __float2half(acc[nt][j]);
      p[j] += acc[nt][j] * av[nt];
    }
  }
#pragma unroll
  for (int m = 1; m < 16; m <<= 1) {
#pragma unroll
    for (int j = 0; j < 4; j++) p[j] += __shfl_xor(p[j], m);
  }
  if (lr == 0) {
#pragma unroll
    for (int j = 0; j < 4; j++) {
      int row = rowb + j;
      if (row < M) a_s[(size_t)row * 4 + h] = p[j];
    }
  }
}

// ---------------- GCN aggregation: wave/dst, 2 lane-groups x 32 lanes, ILP-4/group ----------------
template <int FIN>
__global__ __launch_bounds__(256) void k_gather(const __half* __restrict__ hh,
                                                const int* __restrict__ rowptr,
                                                const int* __restrict__ adj,
                                                const float* __restrict__ dis,
                                                const float* __restrict__ b,
                                                const float* __restrict__ watt,
                                                void* __restrict__ outv, int n) {
  int wid = threadIdx.x >> 6;
  int lane = threadIdx.x & 63;
  int g = lane >> 5;   // 0/1 — neighbor-list split
  int sl = lane & 31;  // column group: 4 halfs each
  int d = blockIdx.x * 4 + wid;
  if (d >= n) return;
  int p0 = rowptr[d], p1 = rowptr[d + 1];
  int c = sl * 4;
  float acc0 = 0.f, acc1 = 0.f, acc2 = 0.f, acc3 = 0.f;
  if (g == 0) {  // self loop
    uint2 v = *(const uint2*)&hh[(size_t)d * 128 + c];
    float2 f0 = __half22float2(*(__half2*)&v.x);
    float2 f1 = __half22float2(*(__half2*)&v.y);
    acc0 = f0.x; acc1 = f0.y; acc2 = f1.x; acc3 = f1.y;
  }
  for (int base = p0; base < p1; base += 64) {
    int remain = p1 - base;
    int m = remain < 64 ? remain : 64;
    int idx = (lane < m) ? adj[base + lane] : 0;
    int j = g;
    for (; j + 6 < m; j += 8) {
      int nb0 = __shfl(idx, j);
      int nb1 = __shfl(idx, j + 2);
      int nb2 = __shfl(idx, j + 4);
      int nb3 = __shfl(idx, j + 6);
      uint2 v0 = *(const uint2*)&hh[(size_t)nb0 * 128 + c];
      uint2 v1 = *(const uint2*)&hh[(size_t)nb1 * 128 + c];
      uint2 v2 = *(const uint2*)&hh[(size_t)nb2 * 128 + c];
      uint2 v3 = *(const uint2*)&hh[(size_t)nb3 * 128 + c];
      float2 a0 = __half22float2(*(__half2*)&v0.x), b0 = __half22float2(*(__half2*)&v0.y);
      float2 a1 = __half22float2(*(__half2*)&v1.x), b1 = __half22float2(*(__half2*)&v1.y);
      float2 a2 = __half22float2(*(__half2*)&v2.x), b2 = __half22float2(*(__half2*)&v2.y);
      float2 a3 = __half22float2(*(__half2*)&v3.x), b3 = __half22float2(*(__half2*)&v3.y);
      acc0 += (a0.x + a1.x) + (a2.x + a3.x);
      acc1 += (a0.y + a1.y) + (a2.y + a3.y);
      acc2 += (b0.x + b1.x) + (b2.x + b3.x);
      acc3 += (b0.y + b1.y) + (b2.y + b3.y);
    }
    for (; j < m; j += 2) {
      int nb = __shfl(idx, j);
      uint2 v = *(const uint2*)&hh[(size_t)nb * 128 + c];
      float2 f0 = __half22float2(*(__half2*)&v.x);
      float2 f1 = __half22float2(*(__half2*)&v.y);
      acc0 += f0.x; acc1 += f0.y; acc2 += f1.x; acc3 += f1.y;
    }
  }
  // combine the two neighbor-split groups
  acc0 += __shfl_xor(acc0, 32);
  acc1 += __shfl_xor(acc1, 32);
  acc2 += __shfl_xor(acc2, 32);
  acc3 += __shfl_xor(acc3, 32);
  float dd = dis[d];
  float x0 = fmaxf(dd * acc0 + b[c], 0.f);
  float x1 = fmaxf(dd * acc1 + b[c + 1], 0.f);
  float x2 = fmaxf(dd * acc2 + b[c + 2], 0.f);
  float x3 = fmaxf(dd * acc3 + b[c + 3], 0.f);
  if (FIN == 1) {
    if (g == 0) {
      __half2 h01 = __floats2half2_rn(x0, x1);
      __half2 h23 = __floats2half2_rn(x2, x3);
      uint2 pk;
      pk.x = *(unsigned*)&h01;
      pk.y = *(unsigned*)&h23;
      *(uint2*)&((__half*)outv)[(size_t)d * 128 + c] = pk;
    }
  } else {
    float p[8];
    const float* w0 = &watt[c * 8];
#pragma unroll
    for (int h = 0; h < 8; h++)
      p[h] = x0 * w0[h] + x1 * w0[8 + h] + x2 * w0[16 + h] + x3 * w0[24 + h];
#pragma unroll
    for (int mm = 1; mm < 32; mm <<= 1) {
#pragma unroll
      for (int h = 0; h < 8; h++) p[h] += __shfl_xor(p[h], mm);
    }
    if (lane == 0) {
      float* o = (float*)outv;
      *(float4*)&o[(size_t)d * 8] = make_float4(p[0], p[1], p[2], p[3]);
      *(float4*)&o[(size_t)d * 8 + 4] = make_float4(p[4], p[5], p[6], p[7]);
    }
  }
}

// ---------------- GAT softmax pass A: denom by dst-gather (regions at NG, 2NG) ----------------
__global__ __launch_bounds__(256) void k_edgeA(const int* __restrict__ rowptr,
                                               const int* __restrict__ adj,
                                               const float* __restrict__ a_s_d,
                                               const float* __restrict__ a_s_c,
                                               const float* __restrict__ att,
                                               float* __restrict__ denom_d,
                                               float* __restrict__ denom_c) {
  int nb1 = (NG + 255) >> 8;
  int blk = blockIdx.x;
  int q = blk >= nb1;
  int d = (blk - (q ? nb1 : 0)) * 256 + threadIdx.x;
  if (d >= NG) return;
  const int* rp = rowptr + NG + (q ? NG : 0);
  const float* a_s = q ? a_s_c : a_s_d;
  float* den = q ? denom_c : denom_d;
  int p0 = rp[d], p1 = rp[d + 1];
  float4 ad4 = *(const float4*)&att[(size_t)d * 8 + q * 4];
  float4 acc = make_float4(0.f, 0.f, 0.f, 0.f);
  for (int p = p0; p < p1; p++) {
    int s = adj[p];
    float4 as4 = *(const float4*)&a_s[(size_t)s * 4];
    float v0 = as4.x + ad4.x, v1 = as4.y + ad4.y, v2 = as4.z + ad4.z, v3 = as4.w + ad4.w;
    v0 = v0 > 0.f ? v0 : 0.2f * v0;
    v1 = v1 > 0.f ? v1 : 0.2f * v1;
    v2 = v2 > 0.f ? v2 : 0.2f * v2;
    v3 = v3 > 0.f ? v3 : 0.2f * v3;
    acc.x += __expf(fminf(v0, 50.f));
    acc.y += __expf(fminf(v1, 50.f));
    acc.z += __expf(fminf(v2, 50.f));
    acc.w += __expf(fminf(v3, 50.f));
  }
  *(float4*)&den[(size_t)d * 4] = acc;
}

// ---------------- GAT softmax pass B: wsrc by src-gather (regions at 3NG, 3NG+NDR) ----------------
__global__ __launch_bounds__(256) void k_edgeB(const int* __restrict__ rowptr,
                                               const int* __restrict__ adj,
                                               const float* __restrict__ a_s_d,
                                               const float* __restrict__ a_s_c,
                                               const float* __restrict__ att,
                                               const float* __restrict__ denom_d,
                                               const float* __restrict__ denom_c,
                                               float* __restrict__ wsrc_d,
                                               float* __restrict__ wsrc_c) {
  int gw = (blockIdx.x * 256 + threadIdx.x) >> 6;
  int lane = threadIdx.x & 63;
  int q = gw >= NDR;
  int s = q ? gw - NDR : gw;
  if (q && s >= NDI) return;
  const int* rp = rowptr + 3 * NG + (q ? NDR : 0);
  const float* a_s = q ? a_s_c : a_s_d;
  const float* den = q ? denom_c : denom_d;
  float* ws = q ? wsrc_c : wsrc_d;
  int p0 = rp[s], p1 = rp[s + 1];
  float4 as4 = *(const float4*)&a_s[(size_t)s * 4];
  int attoff = q * 4;
  float4 acc = make_float4(0.f, 0.f, 0.f, 0.f);
  for (int p = p0 + lane; p < p1; p += 64) {
    int d = adj[p];
    float4 ad4 = *(const float4*)&att[(size_t)d * 8 + attoff];
    float4 dn = *(const float4*)&den[(size_t)d * 4];
    float v0 = as4.x + ad4.x, v1 = as4.y + ad4.y, v2 = as4.z + ad4.z, v3 = as4.w + ad4.w;
    v0 = v0 > 0.f ? v0 : 0.2f * v0;
    v1 = v1 > 0.f ? v1 : 0.2f * v1;
    v2 = v2 > 0.f ? v2 : 0.2f * v2;
    v3 = v3 > 0.f ? v3 : 0.2f * v3;
    acc.x += __expf(fminf(v0, 50.f)) / (dn.x + 1e-16f);
    acc.y += __expf(fminf(v1, 50.f)) / (dn.y + 1e-16f);
    acc.z += __expf(fminf(v2, 50.f)) / (dn.z + 1e-16f);
    acc.w += __expf(fminf(v3, 50.f)) / (dn.w + 1e-16f);
  }
#pragma unroll
  for (int m = 1; m < 64; m <<= 1) {
    acc.x += __shfl_xor(acc.x, m);
    acc.y += __shfl_xor(acc.y, m);
    acc.z += __shfl_xor(acc.z, m);
    acc.w += __shfl_xor(acc.w, m);
  }
  if (lane == 0) *(float4*)&ws[(size_t)s * 4] = acc;
}

// ---------------- fused weighted column sums + embedding column sums ----------------
__global__ __launch_bounds__(512) void k_sum(const __half* __restrict__ hs_d,
                                             const float* __restrict__ wsrc_d,
                                             float* __restrict__ S_d,
                                             const __half* __restrict__ hs_c,
                                             const float* __restrict__ wsrc_c,
                                             float* __restrict__ S_c,
                                             const float* __restrict__ xd,
                                             float* __restrict__ od,
                                             const float* __restrict__ xc,
                                             float* __restrict__ oc) {
  int t = threadIdx.x;
  const int nws_d = (NDR + 63) >> 6;
  const int nws_c = (NDI + 63) >> 6;
  const int ncs_d = (NDR + 511) >> 9;
  int blk = blockIdx.x;
  if (blk < nws_d + nws_c) {
    int q = blk >= nws_d;
    const __half* hs = q ? hs_c : hs_d;
    const float* wsrc = q ? wsrc_c : wsrc_d;
    float* S = q ? S_c : S_d;
    int N = q ? NDI : NDR;
    int r0 = (q ? blk - nws_d : blk) * 64;
    int h = t >> 7;
    int r1 = min(r0 + 64, N);
    float acc = 0.f;
    for (int r = r0; r < r1; r++) acc += wsrc[r * 4 + h] * __half2float(hs[(size_t)r * 512 + t]);
    atomAddF(&S[t], acc);
  } else {
    int cb = blk - nws_d - nws_c;
    int q = cb >= ncs_d;
    const float* x = q ? xc : xd;
    float* o = q ? oc : od;
    int N = q ? NDI : NDR;
    int r0 = (q ? cb - ncs_d : cb) * 512 + (t >> 7) * 128;
    int col = t & 127;
    int r1 = min(r0 + 128, N);
    float acc = 0.f;
    for (int r = r0; r < r1; r++) acc += x[(size_t)r * 128 + col];
    if (r0 < N) atomAddF(&o[col], acc);
  }
}

// ---------------- final fuse ----------------
__global__ __launch_bounds__(128) void k_final(const float* __restrict__ S_d,
                                               const float* __restrict__ S_c,
                                               const float* __restrict__ bdsum,
                                               const float* __restrict__ bcsum,
                                               const float* __restrict__ bd_bias,
                                               const float* __restrict__ bc_bias,
                                               const float* __restrict__ fuse_w,
                                               const float* __restrict__ fuse_b,
                                               float* __restrict__ out) {
  __shared__ float cat[384];
  int t = threadIdx.x;
  float sd = S_d[t] + S_d[128 + t] + S_d[256 + t] + S_d[384 + t];
  float sc = S_c[t] + S_c[128 + t] + S_c[256 + t] + S_c[384 + t];
  const float inv = 1.0f / (4.0f * (float)NG);
  cat[t] = 0.5f * (sd * inv + bd_bias[t] + sc * inv + bc_bias[t]);
  cat[128 + t] = bdsum[t] * (1.0f / (float)NDR);
  cat[256 + t] = bcsum[t] * (1.0f / (float)NDI);
  __syncthreads();
  float o = fuse_b[t];
  for (int k = 0; k < 384; k++) o += cat[k] * fuse_w[k * 128 + t];
  out[t] = o;
}

// ---------------- host launch ----------------
extern "C" void kernel_launch(void* const* d_in, const int* in_sizes, int n_in,
                              void* d_out, int out_size, void* d_ws, size_t ws_size,
                              hipStream_t stream) {
  const float* gene_nodes   = (const float*)d_in[0];
  const int*   drug_edges   = (const int*)d_in[1];
  const int*   dise_edges   = (const int*)d_in[2];
  const int*   gene_edges   = (const int*)d_in[3];
  const float* gcn1_w       = (const float*)d_in[4];
  const float* gcn1_b       = (const float*)d_in[5];
  const float* gcn2_w       = (const float*)d_in[6];
  const float* gcn2_b       = (const float*)d_in[7];
  const float* drug_embed   = (const float*)d_in[8];
  const float* dise_embed   = (const float*)d_in[9];
  const float* gat_d_w      = (const float*)d_in[10];
  const float* gat_d_att_s  = (const float*)d_in[11];
  const float* gat_d_att_d  = (const float*)d_in[12];
  const float* gat_d_b      = (const float*)d_in[13];
  const float* gat_c_w      = (const float*)d_in[14];
  const float* gat_c_att_s  = (const float*)d_in[15];
  const float* gat_c_att_d  = (const float*)d_in[16];
  const float* gat_c_b      = (const float*)d_in[17];
  const float* fuse_w       = (const float*)d_in[18];
  const float* fuse_b       = (const float*)d_in[19];
  const int Ed = in_sizes[1] / 2;
  const int Ec = in_sizes[2] / 2;
  const int Eg = in_sizes[3] / 2;
  float* out = (float*)d_out;
  (void)n_in; (void)out_size; (void)ws_size;

  const int NBS = cdiv_h(NDOM, 1024);   // 308 scan blocks

  // workspace layout (zero-init region first, single memset)
  char* w = (char*)d_ws;
  auto alloc = [&](size_t n) {
    char* p = w;
    w += (n + 511) & ~(size_t)511;
    return p;
  };
  char* z0 = w;
  unsigned* deg     = (unsigned*)alloc((size_t)NDOM * 4);
  float* S_d        = (float*)alloc(512 * 4);
  float* S_c        = (float*)alloc(512 * 4);
  float* bdsum      = (float*)alloc(512);
  float* bcsum      = (float*)alloc(512);
  size_t zbytes = (size_t)(w - z0);
  float* denom_d    = (float*)alloc((size_t)NG * 16);
  float* denom_c    = (float*)alloc((size_t)NG * 16);
  float* wsrc_d     = (float*)alloc((size_t)NDR * 16);
  float* wsrc_c     = (float*)alloc((size_t)NDI * 16);
  float* dis        = (float*)alloc((size_t)NG * 4);
  float* watt       = (float*)alloc(128 * 8 * 4);
  float* att        = (float*)alloc((size_t)NG * 8 * 4);
  float* a_s_d      = (float*)alloc((size_t)NDR * 16);
  float* a_s_c      = (float*)alloc((size_t)NDI * 16);
  unsigned* partial = (unsigned*)alloc((size_t)512 * 4);
  int* rowptr       = (int*)alloc((size_t)(NDOM + 1) * 4);
  int* cursor       = (int*)alloc((size_t)NDOM * 4);
  int* adj          = (int*)alloc((size_t)(Eg + 2 * (Ed + Ec)) * 4);
  __half* Wt1       = (__half*)alloc((size_t)128 * 128 * 2);
  __half* Wt2       = (__half*)alloc((size_t)128 * 128 * 2);
  __half* Wtd       = (__half*)alloc((size_t)512 * 128 * 2);
  __half* Wtc       = (__half*)alloc((size_t)512 * 128 * 2);
  __half* hh        = (__half*)alloc((size_t)NG * 128 * 2);
  __half* x1        = (__half*)alloc((size_t)NG * 128 * 2);
  __half* hs_d      = (__half*)alloc((size_t)NDR * 512 * 2);
  __half* hs_c      = (__half*)alloc((size_t)NDI * 512 * 2);

  hipMemsetAsync(z0, 0, zbytes, stream);

  // CSR build: XCD-sliced deg -> scan -> rowptr(+cursor,+dis) -> XCD-sliced fill
  int nch = cdiv_h(Eg, 1024) + cdiv_h(Ed, 1024) + cdiv_h(Ec, 1024);
  k_build<0><<<nch * 8, 256, 0, stream>>>(gene_edges, Eg, drug_edges, Ed, dise_edges, Ec,
                                          deg, nullptr, nullptr);
  k_blocksum4<<<NBS, 256, 0, stream>>>(deg, partial, NDOM);
  k_scanpart<<<1, 512, 0, stream>>>(partial, NBS);
  k_rowptrAll<<<NBS, 256, 0, stream>>>(deg, partial, NDOM, rowptr, cursor, dis);
  k_build<1><<<nch * 8, 256, 0, stream>>>(gene_edges, Eg, drug_edges, Ed, dise_edges, Ec,
                                          deg, cursor, adj);
  k_prep<<<11, 256, 0, stream>>>(gcn1_w, gcn2_w, gat_d_w, gat_c_w, gat_d_att_d, gat_c_att_d,
                                 Wt1, Wt2, Wtd, Wtc, watt);

  // GCN layer 1
  k_mgemm<0><<<cdiv_h(NG, 64), 256, 0, stream>>>(gene_nodes, Wt1, NG, dis, hh);
  k_gather<1><<<cdiv_h(NG, 4), 256, 0, stream>>>(hh, rowptr, adj, dis, gcn1_b, nullptr, x1, NG);

  // GCN layer 2 (f16 input; att-score epilogue; x2 never materialized)
  k_mgemm<1><<<cdiv_h(NG, 64), 256, 0, stream>>>(x1, Wt2, NG, dis, hh);
  k_gather<2><<<cdiv_h(NG, 4), 256, 0, stream>>>(hh, rowptr, adj, dis, gcn2_b, watt, att, NG);

  // GAT source transforms (both graphs, one launch)
  k_mgat<<<dim3(cdiv_h(NDR, 64) + cdiv_h(NDI, 64), 4), 256, 0, stream>>>(
      drug_embed, dise_embed, Wtd, Wtc, gat_d_att_s, gat_c_att_s, hs_d, hs_c, a_s_d, a_s_c);

  // GAT softmax: denom by dst-gather, wsrc by src-gather (no atomics)
  k_edgeA<<<2 * cdiv_h(NG, 256), 256, 0, stream>>>(rowptr, adj, a_s_d, a_s_c, att, denom_d, denom_c);
  k_edgeB<<<cdiv_h((NDR + NDI) * 64, 256), 256, 0, stream>>>(rowptr, adj, a_s_d, a_s_c, att,
                                                             denom_d, denom_c, wsrc_d, wsrc_c);

  // fused weighted column sums + embedding means
  int nsum = (cdiv_h(NDR, 64) + cdiv_h(NDI, 64)) + (cdiv_h(NDR, 512) + cdiv_h(NDI, 512));
  k_sum<<<nsum, 512, 0, stream>>>(hs_d, wsrc_d, S_d, hs_c, wsrc_c, S_c,
                                  drug_embed, bdsum, dise_embed, bcsum);

  // final fuse
  k_final<<<1, 128, 0, stream>>>(S_d, S_c, bdsum, bcsum, gat_d_b, gat_c_b, fuse_w, fuse_b, out);
}

// Round 10
// 496.507 us; speedup vs baseline: 4.2147x; 1.0993x over previous
//
#include <hip/hip_runtime.h>
#include <hip/hip_fp16.h>

#define NG 100000
#define NDR 10000
#define NDI 5000
#define NDOM (3 * NG + NDR + NDI)   // 315000 combined node domain
#define SL 39375                    // NDOM / 8 node-range slice (exact)

typedef _Float16 f16x8 __attribute__((ext_vector_type(8)));
typedef float f32x4 __attribute__((ext_vector_type(4)));

__device__ __forceinline__ void atomAddF(float* p, float v) { unsafeAtomicAdd(p, v); }

static inline int cdiv_h(int a, int b) { return (a + b - 1) / b; }

// ---------------- XCD-sliced CSR build: PASS 0 = degree count, PASS 1 = cursor fill ----------------
template <int PASS>
__global__ __launch_bounds__(256) void k_build(const int* __restrict__ ge, int Eg_,
                                               const int* __restrict__ de, int Ed_,
                                               const int* __restrict__ ce, int Ec_,
                                               unsigned* __restrict__ deg,
                                               int* __restrict__ cursor,
                                               int* __restrict__ adj) {
  const unsigned slice = blockIdx.x & 7;
  const int chunk = blockIdx.x >> 3;
  const unsigned lo = slice * SL;
  const int nb_g = (Eg_ + 1023) >> 10, nb_d = (Ed_ + 1023) >> 10;
  const int* src;
  const int* dst;
  int E, cb, mode;
  unsigned offD = 0, offS = 0;
  if (chunk < nb_g) {
    src = ge; dst = ge + Eg_; E = Eg_; cb = chunk; mode = 0;
  } else if (chunk < nb_g + nb_d) {
    src = de; dst = de + Ed_; E = Ed_; cb = chunk - nb_g; mode = 1;
    offD = NG; offS = 3 * NG;
  } else {
    src = ce; dst = ce + Ec_; E = Ec_; cb = chunk - nb_g - nb_d; mode = 2;
    offD = 2 * NG; offS = 3 * NG + NDR;
  }
  int e0 = (cb << 10) + (int)threadIdx.x * 4;
  if (e0 >= E) return;
  int4 s4, d4;
  if (e0 + 3 < E) {
    s4 = *(const int4*)&src[e0];
    d4 = *(const int4*)&dst[e0];
  } else {
    int* sp = (int*)&s4;
    int* dp = (int*)&d4;
    for (int j = 0; j < 4; j++) {
      sp[j] = (e0 + j < E) ? src[e0 + j] : 0;
      dp[j] = (e0 + j < E) ? dst[e0 + j] : 0;
    }
  }
  const int* sp = (const int*)&s4;
  const int* dp = (const int*)&d4;
#pragma unroll
  for (int j = 0; j < 4; j++) {
    if (e0 + j >= E) break;
    unsigned nd = offD + (unsigned)dp[j];
    if (nd - lo < SL) {
      if (PASS == 0) {
        atomicAdd(&deg[nd], 1u);
      } else {
        int p = atomicAdd(&cursor[nd], 1);
        adj[p] = sp[j];
      }
    }
    if (mode != 0) {
      unsigned ns = offS + (unsigned)sp[j];
      if (ns - lo < SL) {
        if (PASS == 0) {
          atomicAdd(&deg[ns], 1u);
        } else {
          int p = atomicAdd(&cursor[ns], 1);
          adj[p] = dp[j];
        }
      }
    }
  }
}

// ---------------- scan (1024 elems/block) ----------------
__global__ __launch_bounds__(256) void k_blocksum4(const unsigned* __restrict__ deg,
                                                   unsigned* __restrict__ partial, int n) {
  __shared__ unsigned s[256];
  int t = threadIdx.x;
  int base = blockIdx.x * 1024 + t * 4;
  unsigned v = 0;
  if (base + 3 < n) {
    uint4 u = *(const uint4*)&deg[base];
    v = u.x + u.y + u.z + u.w;
  } else {
    for (int j = 0; j < 4; j++)
      if (base + j < n) v += deg[base + j];
  }
  s[t] = v;
  __syncthreads();
  for (int off = 128; off; off >>= 1) {
    if (t < off) s[t] += s[t + off];
    __syncthreads();
  }
  if (!t) partial[blockIdx.x] = s[0];
}

__global__ __launch_bounds__(512) void k_scanpart(unsigned* __restrict__ partial, int nb) {
  __shared__ unsigned s[512];
  int t = threadIdx.x;
  unsigned v = (t < nb) ? partial[t] : 0u;
  s[t] = v;
  __syncthreads();
  for (int off = 1; off < 512; off <<= 1) {
    unsigned add = (t >= off) ? s[t - off] : 0u;
    __syncthreads();
    s[t] += add;
    __syncthreads();
  }
  if (t < nb) partial[t] = s[t] - v;  // exclusive
}

__global__ __launch_bounds__(256) void k_rowptrAll(const unsigned* __restrict__ deg,
                                                   const unsigned* __restrict__ partial, int n,
                                                   int* __restrict__ rowptr,
                                                   int* __restrict__ cursor,
                                                   float* __restrict__ dis) {
  __shared__ unsigned s[256];
  int t = threadIdx.x;
  int base = blockIdx.x * 1024 + t * 4;
  unsigned v[4] = {0u, 0u, 0u, 0u};
  if (base + 3 < n) {
    uint4 u = *(const uint4*)&deg[base];
    v[0] = u.x; v[1] = u.y; v[2] = u.z; v[3] = u.w;
  } else {
    for (int j = 0; j < 4; j++)
      if (base + j < n) v[j] = deg[base + j];
  }
  unsigned sum4 = v[0] + v[1] + v[2] + v[3];
  s[t] = sum4;
  __syncthreads();
  for (int off = 1; off < 256; off <<= 1) {
    unsigned add = (t >= off) ? s[t - off] : 0u;
    __syncthreads();
    s[t] += add;
    __syncthreads();
  }
  unsigned e = s[t] - sum4 + partial[blockIdx.x];
  for (int j = 0; j < 4; j++) {
    int i = base + j;
    if (i < n) {
      rowptr[i] = (int)e;
      cursor[i] = (int)e;
      if (i < NG) dis[i] = rsqrtf((float)v[j] + 1.0f);
      if (i == n - 1) rowptr[n] = (int)(e + v[j]);
      e += v[j];
    }
  }
}

// ---------------- prep: transpose weights to f16 [n][k] + watt ----------------
__global__ __launch_bounds__(256) void k_prep(const float* __restrict__ W1,
                                              const float* __restrict__ W2,
                                              const float* __restrict__ Wd,
                                              const float* __restrict__ Wc,
                                              const float* __restrict__ attd_d,
                                              const float* __restrict__ attd_c,
                                              __half* __restrict__ Wt1,
                                              __half* __restrict__ Wt2,
                                              __half* __restrict__ Wtd,
                                              __half* __restrict__ Wtc,
                                              float* __restrict__ watt) {
  int blk = blockIdx.x;
  if (blk == 10) {
    int t = threadIdx.x;
    for (int slot = t; slot < 1024; slot += 256) {
      int i = slot >> 3, s8 = slot & 7;
      const float* W = (s8 < 4) ? Wd : Wc;
      const float* A = (s8 < 4) ? attd_d : attd_c;
      int h = s8 & 3;
      float s = 0.f;
      for (int cc = 0; cc < 128; cc++) s += W[(size_t)i * 512 + h * 128 + cc] * A[h * 128 + cc];
      watt[i * 8 + s8] = s;
    }
    return;
  }
  const float* W;
  __half* Wt;
  int N, base;
  if (blk == 0) { W = W1; Wt = Wt1; N = 128; base = 0; }
  else if (blk == 1) { W = W2; Wt = Wt2; N = 128; base = 0; }
  else if (blk < 6) { W = Wd; Wt = Wtd; N = 512; base = (blk - 2) * 16384; }
  else { W = Wc; Wt = Wtc; N = 512; base = (blk - 6) * 16384; }
  for (int q = threadIdx.x; q < 16384; q += 256) {
    int qq = base + q;
    int n = qq >> 7, k = qq & 127;
    Wt[qq] = __float2half(W[(size_t)k * N + n]);
  }
}

// ---------------- MFMA f16 GEMM: hh[M,128] = (X[M,128] @ W) * dis[row], f16 out ----------------
template <int INF16>
__global__ __launch_bounds__(256) void k_mgemm(const void* __restrict__ Xv,
                                               const __half* __restrict__ Wt, int M,
                                               const float* __restrict__ dis,
                                               __half* __restrict__ hh) {
  __shared__ __align__(16) char lds[48 * 1024];
  char* As = lds;              // 64 x 128 f16 = 16 KB
  char* Bs = lds + 16 * 1024;  // 128 x 128 f16 = 32 KB
  const int t = threadIdx.x;
  const int row0 = blockIdx.x * 64;

#pragma unroll
  for (int rep = 0; rep < 8; rep++) {
    int q = t + rep * 256;
    int r = q >> 4, c16 = (q & 15) * 16;
    uint4 v = *(const uint4*)((const char*)Wt + r * 256 + c16);
    *(uint4*)(Bs + ((r * 256 + c16) ^ ((r & 7) << 4))) = v;
  }
  if (INF16 == 0) {
    const float* X = (const float*)Xv;
#pragma unroll
    for (int rep = 0; rep < 8; rep++) {
      int q = t + rep * 256;
      int r = q >> 5, c4 = (q & 31) * 4;
      int gr = row0 + r;
      float4 xv = make_float4(0.f, 0.f, 0.f, 0.f);
      if (gr < M) xv = *(const float4*)&X[(size_t)gr * 128 + c4];
      __half2 h0 = __floats2half2_rn(xv.x, xv.y);
      __half2 h1 = __floats2half2_rn(xv.z, xv.w);
      uint2 pk;
      pk.x = *(unsigned*)&h0;
      pk.y = *(unsigned*)&h1;
      *(uint2*)(As + ((r * 256 + c4 * 2) ^ ((r & 7) << 4))) = pk;
    }
  } else {
    const __half* X = (const __half*)Xv;
#pragma unroll
    for (int rep = 0; rep < 4; rep++) {
      int q = t + rep * 256;
      int r = q >> 4, c16 = (q & 15) * 16;
      int gr = row0 + r;
      uint4 v = make_uint4(0u, 0u, 0u, 0u);
      if (gr < M) v = *(const uint4*)((const char*)X + (size_t)gr * 256 + c16);
      *(uint4*)(As + ((r * 256 + c16) ^ ((r & 7) << 4))) = v;
    }
  }
  __syncthreads();

  const int w = t >> 6, l = t & 63;
  const int lr = l & 15, lk = l >> 4;
  f32x4 acc[8] = {};
#pragma unroll
  for (int s = 0; s < 4; s++) {
    int arow = w * 16 + lr;
    f16x8 a = *(const f16x8*)(As + ((arow * 256 + lk * 16 + s * 64) ^ ((arow & 7) << 4)));
#pragma unroll
    for (int nt = 0; nt < 8; nt++) {
      int brow = nt * 16 + lr;
      f16x8 b = *(const f16x8*)(Bs + ((brow * 256 + lk * 16 + s * 64) ^ ((brow & 7) << 4)));
      acc[nt] = __builtin_amdgcn_mfma_f32_16x16x32_f16(a, b, acc[nt], 0, 0, 0);
    }
  }
  float ddv[4];
  int rowb = row0 + w * 16 + lk * 4;
#pragma unroll
  for (int j = 0; j < 4; j++) ddv[j] = (rowb + j < M) ? dis[rowb + j] : 0.f;
#pragma unroll
  for (int nt = 0; nt < 8; nt++) {
#pragma unroll
    for (int j = 0; j < 4; j++) {
      int row = rowb + j;
      if (row < M) hh[(size_t)row * 128 + nt * 16 + lr] = __float2half(acc[nt][j] * ddv[j]);
    }
  }
}

// ---------------- MFMA f16 GAT GEMM (drug+disease in one launch) ----------------
__global__ __launch_bounds__(256) void k_mgat(const float* __restrict__ Xd,
                                              const float* __restrict__ Xc,
                                              const __half* __restrict__ Wtd,
                                              const __half* __restrict__ Wtc,
                                              const float* __restrict__ attSd,
                                              const float* __restrict__ attSc,
                                              __half* __restrict__ hsd,
                                              __half* __restrict__ hsc,
                                              float* __restrict__ a_s_d,
                                              float* __restrict__ a_s_c) {
  __shared__ __align__(16) char lds[48 * 1024];
  char* As = lds;
  char* Bs = lds + 16 * 1024;
  const int t = threadIdx.x;
  const int nbd = (NDR + 63) >> 6;
  const int q = blockIdx.x >= nbd;
  const int bx = q ? blockIdx.x - nbd : blockIdx.x;
  const int M = q ? NDI : NDR;
  const float* X = q ? Xc : Xd;
  const __half* Wt = q ? Wtc : Wtd;
  const float* attS = q ? attSc : attSd;
  __half* hs = q ? hsc : hsd;
  float* a_s = q ? a_s_c : a_s_d;
  const int row0 = bx * 64;
  const int h = blockIdx.y;
  const __half* Wth = Wt + (size_t)h * 128 * 128;

#pragma unroll
  for (int rep = 0; rep < 8; rep++) {
    int r = (t + rep * 256) >> 4, c16 = ((t + rep * 256) & 15) * 16;
    uint4 v = *(const uint4*)((const char*)Wth + r * 256 + c16);
    *(uint4*)(Bs + ((r * 256 + c16) ^ ((r & 7) << 4))) = v;
  }
#pragma unroll
  for (int rep = 0; rep < 8; rep++) {
    int qq = t + rep * 256;
    int r = qq >> 5, c4 = (qq & 31) * 4;
    int gr = row0 + r;
    float4 xv = make_float4(0.f, 0.f, 0.f, 0.f);
    if (gr < M) xv = *(const float4*)&X[(size_t)gr * 128 + c4];
    __half2 h0 = __floats2half2_rn(xv.x, xv.y);
    __half2 h1 = __floats2half2_rn(xv.z, xv.w);
    uint2 pk;
    pk.x = *(unsigned*)&h0;
    pk.y = *(unsigned*)&h1;
    *(uint2*)(As + ((r * 256 + c4 * 2) ^ ((r & 7) << 4))) = pk;
  }
  __syncthreads();

  const int w = t >> 6, l = t & 63;
  const int lr = l & 15, lk = l >> 4;
  f32x4 acc[8] = {};
#pragma unroll
  for (int s = 0; s < 4; s++) {
    int arow = w * 16 + lr;
    f16x8 a = *(const f16x8*)(As + ((arow * 256 + lk * 16 + s * 64) ^ ((arow & 7) << 4)));
#pragma unroll
    for (int nt = 0; nt < 8; nt++) {
      int brow = nt * 16 + lr;
      f16x8 b = *(const f16x8*)(Bs + ((brow * 256 + lk * 16 + s * 64) ^ ((brow & 7) << 4)));
      acc[nt] = __builtin_amdgcn_mfma_f32_16x16x32_f16(a, b, acc[nt], 0, 0, 0);
    }
  }
  float av[8];
#pragma unroll
  for (int nt = 0; nt < 8; nt++) av[nt] = attS[h * 128 + nt * 16 + lr];

  int rowb = row0 + w * 16 + lk * 4;
  float p[4] = {0.f, 0.f, 0.f, 0.f};
#pragma unroll
  for (int nt = 0; nt < 8; nt++) {
#pragma unroll
    for (int j = 0; j < 4; j++) {
      int row = rowb + j;
      if (row < M) hs[(size_t)row * 512 + h * 128 + nt * 16 + lr] = __float2half(acc[nt][j]);
      p[j] += acc[nt][j] * av[nt];
    }
  }
#pragma unroll
  for (int m = 1; m < 16; m <<= 1) {
#pragma unroll
    for (int j = 0; j < 4; j++) p[j] += __shfl_xor(p[j], m);
  }
  if (lr == 0) {
#pragma unroll
    for (int j = 0; j < 4; j++) {
      int row = rowb + j;
      if (row < M) a_s[(size_t)row * 4 + h] = p[j];
    }
  }
}

// ---------------- GCN aggregation: CSR gather, wave/dst + ILP-8 (proven R7 layout) ----------------
// FIN 1: out = x1 row f16; FIN 2: out = att row (8 scores fp32)
template <int FIN>
__global__ __launch_bounds__(256) void k_gather(const __half* __restrict__ hh,
                                                const int* __restrict__ rowptr,
                                                const int* __restrict__ adj,
                                                const float* __restrict__ dis,
                                                const float* __restrict__ b,
                                                const float* __restrict__ watt,
                                                void* __restrict__ outv, int n) {
  int wid = threadIdx.x >> 6;
  int lane = threadIdx.x & 63;
  int d = blockIdx.x * 4 + wid;
  if (d >= n) return;
  int p0 = rowptr[d], p1 = rowptr[d + 1];
  int c = lane * 2;
  float2 s;
  {
    unsigned v = *(const unsigned*)&hh[(size_t)d * 128 + c];  // self loop
    s = __half22float2(*(__half2*)&v);
  }
  for (int base = p0; base < p1; base += 64) {
    int remain = p1 - base;
    int m = remain < 64 ? remain : 64;
    int idx = (lane < m) ? adj[base + lane] : 0;
    int j = 0;
    for (; j + 8 <= m; j += 8) {
      int nb[8];
      unsigned v[8];
#pragma unroll
      for (int u = 0; u < 8; u++) nb[u] = __shfl(idx, j + u);
#pragma unroll
      for (int u = 0; u < 8; u++) v[u] = *(const unsigned*)&hh[(size_t)nb[u] * 128 + c];
#pragma unroll
      for (int u = 0; u < 8; u++) {
        float2 f = __half22float2(*(__half2*)&v[u]);
        s.x += f.x;
        s.y += f.y;
      }
    }
    for (; j + 4 <= m; j += 4) {
      int nb[4];
      unsigned v[4];
#pragma unroll
      for (int u = 0; u < 4; u++) nb[u] = __shfl(idx, j + u);
#pragma unroll
      for (int u = 0; u < 4; u++) v[u] = *(const unsigned*)&hh[(size_t)nb[u] * 128 + c];
#pragma unroll
      for (int u = 0; u < 4; u++) {
        float2 f = __half22float2(*(__half2*)&v[u]);
        s.x += f.x;
        s.y += f.y;
      }
    }
    for (; j < m; j++) {
      int nb = __shfl(idx, j);
      unsigned v = *(const unsigned*)&hh[(size_t)nb * 128 + c];
      float2 f = __half22float2(*(__half2*)&v);
      s.x += f.x;
      s.y += f.y;
    }
  }
  float dd = dis[d];
  float x0 = fmaxf(dd * s.x + b[c], 0.f);
  float x1v = fmaxf(dd * s.y + b[c + 1], 0.f);
  if (FIN == 1) {
    __half* o = (__half*)outv;
    __half2 hv = __floats2half2_rn(x0, x1v);
    *(__half2*)&o[(size_t)d * 128 + c] = hv;
  } else {
    float* o = (float*)outv;
    float p[8];
    const float* w0 = &watt[c * 8];
#pragma unroll
    for (int h = 0; h < 8; h++) p[h] = x0 * w0[h] + x1v * w0[8 + h];
#pragma unroll
    for (int mm = 32; mm; mm >>= 1) {
#pragma unroll
      for (int h = 0; h < 8; h++) p[h] += __shfl_xor(p[h], mm);
    }
    if (lane == 0) {
      *(float4*)&o[(size_t)d * 8] = make_float4(p[0], p[1], p[2], p[3]);
      *(float4*)&o[(size_t)d * 8 + 4] = make_float4(p[4], p[5], p[6], p[7]);
    }
  }
}

// ---------------- GAT softmax pass A: denom by dst-gather (regions at NG, 2NG) ----------------
__global__ __launch_bounds__(256) void k_edgeA(const int* __restrict__ rowptr,
                                               const int* __restrict__ adj,
                                               const float* __restrict__ a_s_d,
                                               const float* __restrict__ a_s_c,
                                               const float* __restrict__ att,
                                               float* __restrict__ denom_d,
                                               float* __restrict__ denom_c) {
  int nb1 = (NG + 255) >> 8;
  int blk = blockIdx.x;
  int q = blk >= nb1;
  int d = (blk - (q ? nb1 : 0)) * 256 + threadIdx.x;
  if (d >= NG) return;
  const int* rp = rowptr + NG + (q ? NG : 0);
  const float* a_s = q ? a_s_c : a_s_d;
  float* den = q ? denom_c : denom_d;
  int p0 = rp[d], p1 = rp[d + 1];
  float4 ad4 = *(const float4*)&att[(size_t)d * 8 + q * 4];
  float4 acc = make_float4(0.f, 0.f, 0.f, 0.f);
  for (int p = p0; p < p1; p++) {
    int s = adj[p];
    float4 as4 = *(const float4*)&a_s[(size_t)s * 4];
    float v0 = as4.x + ad4.x, v1 = as4.y + ad4.y, v2 = as4.z + ad4.z, v3 = as4.w + ad4.w;
    v0 = v0 > 0.f ? v0 : 0.2f * v0;
    v1 = v1 > 0.f ? v1 : 0.2f * v1;
    v2 = v2 > 0.f ? v2 : 0.2f * v2;
    v3 = v3 > 0.f ? v3 : 0.2f * v3;
    acc.x += __expf(fminf(v0, 50.f));
    acc.y += __expf(fminf(v1, 50.f));
    acc.z += __expf(fminf(v2, 50.f));
    acc.w += __expf(fminf(v3, 50.f));
  }
  *(float4*)&den[(size_t)d * 4] = acc;
}

// ---------------- GAT softmax pass B: wsrc by src-gather (regions at 3NG, 3NG+NDR) ----------------
__global__ __launch_bounds__(256) void k_edgeB(const int* __restrict__ rowptr,
                                               const int* __restrict__ adj,
                                               const float* __restrict__ a_s_d,
                                               const float* __restrict__ a_s_c,
                                               const float* __restrict__ att,
                                               const float* __restrict__ denom_d,
                                               const float* __restrict__ denom_c,
                                               float* __restrict__ wsrc_d,
                                               float* __restrict__ wsrc_c) {
  int gw = (blockIdx.x * 256 + threadIdx.x) >> 6;
  int lane = threadIdx.x & 63;
  int q = gw >= NDR;
  int s = q ? gw - NDR : gw;
  if (q && s >= NDI) return;
  const int* rp = rowptr + 3 * NG + (q ? NDR : 0);
  const float* a_s = q ? a_s_c : a_s_d;
  const float* den = q ? denom_c : denom_d;
  float* ws = q ? wsrc_c : wsrc_d;
  int p0 = rp[s], p1 = rp[s + 1];
  float4 as4 = *(const float4*)&a_s[(size_t)s * 4];
  int attoff = q * 4;
  float4 acc = make_float4(0.f, 0.f, 0.f, 0.f);
  for (int p = p0 + lane; p < p1; p += 64) {
    int d = adj[p];
    float4 ad4 = *(const float4*)&att[(size_t)d * 8 + attoff];
    float4 dn = *(const float4*)&den[(size_t)d * 4];
    float v0 = as4.x + ad4.x, v1 = as4.y + ad4.y, v2 = as4.z + ad4.z, v3 = as4.w + ad4.w;
    v0 = v0 > 0.f ? v0 : 0.2f * v0;
    v1 = v1 > 0.f ? v1 : 0.2f * v1;
    v2 = v2 > 0.f ? v2 : 0.2f * v2;
    v3 = v3 > 0.f ? v3 : 0.2f * v3;
    acc.x += __expf(fminf(v0, 50.f)) / (dn.x + 1e-16f);
    acc.y += __expf(fminf(v1, 50.f)) / (dn.y + 1e-16f);
    acc.z += __expf(fminf(v2, 50.f)) / (dn.z + 1e-16f);
    acc.w += __expf(fminf(v3, 50.f)) / (dn.w + 1e-16f);
  }
#pragma unroll
  for (int m = 1; m < 64; m <<= 1) {
    acc.x += __shfl_xor(acc.x, m);
    acc.y += __shfl_xor(acc.y, m);
    acc.z += __shfl_xor(acc.z, m);
    acc.w += __shfl_xor(acc.w, m);
  }
  if (lane == 0) *(float4*)&ws[(size_t)s * 4] = acc;
}

// ---------------- fused weighted column sums + embedding column sums ----------------
__global__ __launch_bounds__(512) void k_sum(const __half* __restrict__ hs_d,
                                             const float* __restrict__ wsrc_d,
                                             float* __restrict__ S_d,
                                             const __half* __restrict__ hs_c,
                                             const float* __restrict__ wsrc_c,
                                             float* __restrict__ S_c,
                                             const float* __restrict__ xd,
                                             float* __restrict__ od,
                                             const float* __restrict__ xc,
                                             float* __restrict__ oc) {
  int t = threadIdx.x;
  const int nws_d = (NDR + 63) >> 6;
  const int nws_c = (NDI + 63) >> 6;
  const int ncs_d = (NDR + 511) >> 9;
  int blk = blockIdx.x;
  if (blk < nws_d + nws_c) {
    int q = blk >= nws_d;
    const __half* hs = q ? hs_c : hs_d;
    const float* wsrc = q ? wsrc_c : wsrc_d;
    float* S = q ? S_c : S_d;
    int N = q ? NDI : NDR;
    int r0 = (q ? blk - nws_d : blk) * 64;
    int h = t >> 7;
    int r1 = min(r0 + 64, N);
    float acc = 0.f;
    for (int r = r0; r < r1; r++) acc += wsrc[r * 4 + h] * __half2float(hs[(size_t)r * 512 + t]);
    atomAddF(&S[t], acc);
  } else {
    int cb = blk - nws_d - nws_c;
    int q = cb >= ncs_d;
    const float* x = q ? xc : xd;
    float* o = q ? oc : od;
    int N = q ? NDI : NDR;
    int r0 = (q ? cb - ncs_d : cb) * 512 + (t >> 7) * 128;
    int col = t & 127;
    int r1 = min(r0 + 128, N);
    float acc = 0.f;
    for (int r = r0; r < r1; r++) acc += x[(size_t)r * 128 + col];
    if (r0 < N) atomAddF(&o[col], acc);
  }
}

// ---------------- final fuse ----------------
__global__ __launch_bounds__(128) void k_final(const float* __restrict__ S_d,
                                               const float* __restrict__ S_c,
                                               const float* __restrict__ bdsum,
                                               const float* __restrict__ bcsum,
                                               const float* __restrict__ bd_bias,
                                               const float* __restrict__ bc_bias,
                                               const float* __restrict__ fuse_w,
                                               const float* __restrict__ fuse_b,
                                               float* __restrict__ out) {
  __shared__ float cat[384];
  int t = threadIdx.x;
  float sd = S_d[t] + S_d[128 + t] + S_d[256 + t] + S_d[384 + t];
  float sc = S_c[t] + S_c[128 + t] + S_c[256 + t] + S_c[384 + t];
  const float inv = 1.0f / (4.0f * (float)NG);
  cat[t] = 0.5f * (sd * inv + bd_bias[t] + sc * inv + bc_bias[t]);
  cat[128 + t] = bdsum[t] * (1.0f / (float)NDR);
  cat[256 + t] = bcsum[t] * (1.0f / (float)NDI);
  __syncthreads();
  float o = fuse_b[t];
  for (int k = 0; k < 384; k++) o += cat[k] * fuse_w[k * 128 + t];
  out[t] = o;
}

// ---------------- host launch ----------------
extern "C" void kernel_launch(void* const* d_in, const int* in_sizes, int n_in,
                              void* d_out, int out_size, void* d_ws, size_t ws_size,
                              hipStream_t stream) {
  const float* gene_nodes   = (const float*)d_in[0];
  const int*   drug_edges   = (const int*)d_in[1];
  const int*   dise_edges   = (const int*)d_in[2];
  const int*   gene_edges   = (const int*)d_in[3];
  const float* gcn1_w       = (const float*)d_in[4];
  const float* gcn1_b       = (const float*)d_in[5];
  const float* gcn2_w       = (const float*)d_in[6];
  const float* gcn2_b       = (const float*)d_in[7];
  const float* drug_embed   = (const float*)d_in[8];
  const float* dise_embed   = (const float*)d_in[9];
  const float* gat_d_w      = (const float*)d_in[10];
  const float* gat_d_att_s  = (const float*)d_in[11];
  const float* gat_d_att_d  = (const float*)d_in[12];
  const float* gat_d_b      = (const float*)d_in[13];
  const float* gat_c_w      = (const float*)d_in[14];
  const float* gat_c_att_s  = (const float*)d_in[15];
  const float* gat_c_att_d  = (const float*)d_in[16];
  const float* gat_c_b      = (const float*)d_in[17];
  const float* fuse_w       = (const float*)d_in[18];
  const float* fuse_b       = (const float*)d_in[19];
  const int Ed = in_sizes[1] / 2;
  const int Ec = in_sizes[2] / 2;
  const int Eg = in_sizes[3] / 2;
  float* out = (float*)d_out;
  (void)n_in; (void)out_size; (void)ws_size;

  const int NBS = cdiv_h(NDOM, 1024);   // 308 scan blocks

  // workspace layout (zero-init region first, single memset)
  char* w = (char*)d_ws;
  auto alloc = [&](size_t n) {
    char* p = w;
    w += (n + 511) & ~(size_t)511;
    return p;
  };
  char* z0 = w;
  unsigned* deg     = (unsigned*)alloc((size_t)NDOM * 4);
  float* S_d        = (float*)alloc(512 * 4);
  float* S_c        = (float*)alloc(512 * 4);
  float* bdsum      = (float*)alloc(512);
  float* bcsum      = (float*)alloc(512);
  size_t zbytes = (size_t)(w - z0);
  float* denom_d    = (float*)alloc((size_t)NG * 16);
  float* denom_c    = (float*)alloc((size_t)NG * 16);
  float* wsrc_d     = (float*)alloc((size_t)NDR * 16);
  float* wsrc_c     = (float*)alloc((size_t)NDI * 16);
  float* dis        = (float*)alloc((size_t)NG * 4);
  float* watt       = (float*)alloc(128 * 8 * 4);
  float* att        = (float*)alloc((size_t)NG * 8 * 4);
  float* a_s_d      = (float*)alloc((size_t)NDR * 16);
  float* a_s_c      = (float*)alloc((size_t)NDI * 16);
  unsigned* partial = (unsigned*)alloc((size_t)512 * 4);
  int* rowptr       = (int*)alloc((size_t)(NDOM + 1) * 4);
  int* cursor       = (int*)alloc((size_t)NDOM * 4);
  int* adj          = (int*)alloc((size_t)(Eg + 2 * (Ed + Ec)) * 4);
  __half* Wt1       = (__half*)alloc((size_t)128 * 128 * 2);
  __half* Wt2       = (__half*)alloc((size_t)128 * 128 * 2);
  __half* Wtd       = (__half*)alloc((size_t)512 * 128 * 2);
  __half* Wtc       = (__half*)alloc((size_t)512 * 128 * 2);
  __half* hh        = (__half*)alloc((size_t)NG * 128 * 2);
  __half* x1        = (__half*)alloc((size_t)NG * 128 * 2);
  __half* hs_d      = (__half*)alloc((size_t)NDR * 512 * 2);
  __half* hs_c      = (__half*)alloc((size_t)NDI * 512 * 2);

  hipMemsetAsync(z0, 0, zbytes, stream);

  // CSR build: XCD-sliced deg -> scan -> rowptr(+cursor,+dis) -> XCD-sliced fill
  int nch = cdiv_h(Eg, 1024) + cdiv_h(Ed, 1024) + cdiv_h(Ec, 1024);
  k_build<0><<<nch * 8, 256, 0, stream>>>(gene_edges, Eg, drug_edges, Ed, dise_edges, Ec,
                                          deg, nullptr, nullptr);
  k_blocksum4<<<NBS, 256, 0, stream>>>(deg, partial, NDOM);
  k_scanpart<<<1, 512, 0, stream>>>(partial, NBS);
  k_rowptrAll<<<NBS, 256, 0, stream>>>(deg, partial, NDOM, rowptr, cursor, dis);
  k_build<1><<<nch * 8, 256, 0, stream>>>(gene_edges, Eg, drug_edges, Ed, dise_edges, Ec,
                                          deg, cursor, adj);
  k_prep<<<11, 256, 0, stream>>>(gcn1_w, gcn2_w, gat_d_w, gat_c_w, gat_d_att_d, gat_c_att_d,
                                 Wt1, Wt2, Wtd, Wtc, watt);

  // GCN layer 1
  k_mgemm<0><<<cdiv_h(NG, 64), 256, 0, stream>>>(gene_nodes, Wt1, NG, dis, hh);
  k_gather<1><<<cdiv_h(NG, 4), 256, 0, stream>>>(hh, rowptr, adj, dis, gcn1_b, nullptr, x1, NG);

  // GCN layer 2 (f16 input; att-score epilogue; x2 never materialized)
  k_mgemm<1><<<cdiv_h(NG, 64), 256, 0, stream>>>(x1, Wt2, NG, dis, hh);
  k_gather<2><<<cdiv_h(NG, 4), 256, 0, stream>>>(hh, rowptr, adj, dis, gcn2_b, watt, att, NG);

  // GAT source transforms (both graphs, one launch)
  k_mgat<<<dim3(cdiv_h(NDR, 64) + cdiv_h(NDI, 64), 4), 256, 0, stream>>>(
      drug_embed, dise_embed, Wtd, Wtc, gat_d_att_s, gat_c_att_s, hs_d, hs_c, a_s_d, a_s_c);

  // GAT softmax: denom by dst-gather, wsrc by src-gather (no atomics)
  k_edgeA<<<2 * cdiv_h(NG, 256), 256, 0, stream>>>(rowptr, adj, a_s_d, a_s_c, att, denom_d, denom_c);
  k_edgeB<<<cdiv_h((NDR + NDI) * 64, 256), 256, 0, stream>>>(rowptr, adj, a_s_d, a_s_c, att,
                                                             denom_d, denom_c, wsrc_d, wsrc_c);

  // fused weighted column sums + embedding means
  int nsum = (cdiv_h(NDR, 64) + cdiv_h(NDI, 64)) + (cdiv_h(NDR, 512) + cdiv_h(NDI, 512));
  k_sum<<<nsum, 512, 0, stream>>>(hs_d, wsrc_d, S_d, hs_c, wsrc_c, S_c,
                                  drug_embed, bdsum, dise_embed, bcsum);

  // final fuse
  k_final<<<1, 128, 0, stream>>>(S_d, S_c, bdsum, bcsum, gat_d_b, gat_c_b, fuse_w, fuse_b, out);
}

// Round 11
// 446.510 us; speedup vs baseline: 4.6867x; 1.1120x over previous
//
#include <hip/hip_runtime.h>
#include <hip/hip_fp16.h>

#define NG 100000
#define NDR 10000
#define NDI 5000
#define NDOM (3 * NG + NDR + NDI)   // 315000 combined node domain
#define SL 39375                    // NDOM / 8 node-range slice (exact)

typedef _Float16 f16x8 __attribute__((ext_vector_type(8)));
typedef float f32x4 __attribute__((ext_vector_type(4)));
typedef int i32x4 __attribute__((ext_vector_type(4)));

__device__ __forceinline__ void atomAddF(float* p, float v) { unsafeAtomicAdd(p, v); }

static inline int cdiv_h(int a, int b) { return (a + b - 1) / b; }

// ---------------- edge-chunk selection helper ----------------
__device__ __forceinline__ void pick_chunk(int chunk, const int* ge, int Eg_,
                                           const int* de, int Ed_,
                                           const int* ce, int Ec_,
                                           const int*& src, const int*& dst, int& E,
                                           int& cb, int& mode, unsigned& offD, unsigned& offS) {
  const int nb_g = (Eg_ + 1023) >> 10, nb_d = (Ed_ + 1023) >> 10;
  offD = 0; offS = 0;
  if (chunk < nb_g) {
    src = ge; dst = ge + Eg_; E = Eg_; cb = chunk; mode = 0;
  } else if (chunk < nb_g + nb_d) {
    src = de; dst = de + Ed_; E = Ed_; cb = chunk - nb_g; mode = 1;
    offD = NG; offS = 3 * NG;
  } else {
    src = ce; dst = ce + Ec_; E = Ec_; cb = chunk - nb_g - nb_d; mode = 2;
    offD = 2 * NG; offS = 3 * NG + NDR;
  }
}

// load 4 edges (nt streaming loads keep adj/cursor lines resident in L2)
__device__ __forceinline__ void load4(const int* __restrict__ src, const int* __restrict__ dst,
                                      int e0, int E, i32x4& s4, i32x4& d4) {
  if (e0 + 3 < E) {
    s4 = __builtin_nontemporal_load((const i32x4*)&src[e0]);
    d4 = __builtin_nontemporal_load((const i32x4*)&dst[e0]);
  } else {
    for (int j = 0; j < 4; j++) {
      s4[j] = (e0 + j < E) ? src[e0 + j] : 0;
      d4[j] = (e0 + j < E) ? dst[e0 + j] : 0;
    }
  }
}

// ---------------- degree body (UNSLICED: deg region is tiny, no line-waste issue) ----------------
__device__ __forceinline__ void deg_body(int chunk, const int* ge, int Eg_,
                                         const int* de, int Ed_,
                                         const int* ce, int Ec_,
                                         unsigned* __restrict__ deg) {
  const int* src; const int* dst; int E, cb, mode; unsigned offD, offS;
  pick_chunk(chunk, ge, Eg_, de, Ed_, ce, Ec_, src, dst, E, cb, mode, offD, offS);
  int e0 = (cb << 10) + (int)threadIdx.x * 4;
  if (e0 >= E) return;
  i32x4 s4, d4;
  load4(src, dst, e0, E, s4, d4);
#pragma unroll
  for (int j = 0; j < 4; j++) {
    if (e0 + j >= E) break;
    atomicAdd(&deg[offD + (unsigned)d4[j]], 1u);
    if (mode != 0) atomicAdd(&deg[offS + (unsigned)s4[j]], 1u);
  }
}

// ---------------- prep body: transpose weights to f16 [n][k] + watt ----------------
__device__ __forceinline__ void prep_body(int blk,
                                          const float* W1, const float* W2,
                                          const float* Wd, const float* Wc,
                                          const float* attd_d, const float* attd_c,
                                          __half* Wt1, __half* Wt2,
                                          __half* Wtd, __half* Wtc, float* watt) {
  if (blk == 10) {
    int t = threadIdx.x;
    for (int slot = t; slot < 1024; slot += 256) {
      int i = slot >> 3, s8 = slot & 7;
      const float* W = (s8 < 4) ? Wd : Wc;
      const float* A = (s8 < 4) ? attd_d : attd_c;
      int h = s8 & 3;
      float s = 0.f;
      for (int cc = 0; cc < 128; cc++) s += W[(size_t)i * 512 + h * 128 + cc] * A[h * 128 + cc];
      watt[i * 8 + s8] = s;
    }
    return;
  }
  const float* W;
  __half* Wt;
  int N, base;
  if (blk == 0) { W = W1; Wt = Wt1; N = 128; base = 0; }
  else if (blk == 1) { W = W2; Wt = Wt2; N = 128; base = 0; }
  else if (blk < 6) { W = Wd; Wt = Wtd; N = 512; base = (blk - 2) * 16384; }
  else { W = Wc; Wt = Wtc; N = 512; base = (blk - 6) * 16384; }
  for (int q = threadIdx.x; q < 16384; q += 256) {
    int qq = base + q;
    int n = qq >> 7, k = qq & 127;
    Wt[qq] = __float2half(W[(size_t)k * N + n]);
  }
}

// ---------------- front kernel: degree (unsliced, nt) || weight prep ----------------
__global__ __launch_bounds__(256) void k_front(const int* __restrict__ ge, int Eg_,
                                               const int* __restrict__ de, int Ed_,
                                               const int* __restrict__ ce, int Ec_,
                                               unsigned* __restrict__ deg,
                                               const float* __restrict__ W1,
                                               const float* __restrict__ W2,
                                               const float* __restrict__ Wd,
                                               const float* __restrict__ Wc,
                                               const float* __restrict__ attd_d,
                                               const float* __restrict__ attd_c,
                                               __half* __restrict__ Wt1,
                                               __half* __restrict__ Wt2,
                                               __half* __restrict__ Wtd,
                                               __half* __restrict__ Wtc,
                                               float* __restrict__ watt) {
  const int nch = ((Eg_ + 1023) >> 10) + ((Ed_ + 1023) >> 10) + ((Ec_ + 1023) >> 10);
  if ((int)blockIdx.x < nch) {
    deg_body(blockIdx.x, ge, Eg_, de, Ed_, ce, Ec_, deg);
    return;
  }
  prep_body(blockIdx.x - nch, W1, W2, Wd, Wc, attd_d, attd_c, Wt1, Wt2, Wtd, Wtc, watt);
}

// ---------------- scan (1024 elems/block) ----------------
__global__ __launch_bounds__(256) void k_blocksum4(const unsigned* __restrict__ deg,
                                                   unsigned* __restrict__ partial, int n) {
  __shared__ unsigned s[256];
  int t = threadIdx.x;
  int base = blockIdx.x * 1024 + t * 4;
  unsigned v = 0;
  if (base + 3 < n) {
    uint4 u = *(const uint4*)&deg[base];
    v = u.x + u.y + u.z + u.w;
  } else {
    for (int j = 0; j < 4; j++)
      if (base + j < n) v += deg[base + j];
  }
  s[t] = v;
  __syncthreads();
  for (int off = 128; off; off >>= 1) {
    if (t < off) s[t] += s[t + off];
    __syncthreads();
  }
  if (!t) partial[blockIdx.x] = s[0];
}

__global__ __launch_bounds__(512) void k_scanpart(unsigned* __restrict__ partial, int nb) {
  __shared__ unsigned s[512];
  int t = threadIdx.x;
  unsigned v = (t < nb) ? partial[t] : 0u;
  s[t] = v;
  __syncthreads();
  for (int off = 1; off < 512; off <<= 1) {
    unsigned add = (t >= off) ? s[t - off] : 0u;
    __syncthreads();
    s[t] += add;
    __syncthreads();
  }
  if (t < nb) partial[t] = s[t] - v;  // exclusive
}

__global__ __launch_bounds__(256) void k_rowptrAll(const unsigned* __restrict__ deg,
                                                   const unsigned* __restrict__ partial, int n,
                                                   int* __restrict__ rowptr,
                                                   int* __restrict__ cursor,
                                                   float* __restrict__ dis) {
  __shared__ unsigned s[256];
  int t = threadIdx.x;
  int base = blockIdx.x * 1024 + t * 4;
  unsigned v[4] = {0u, 0u, 0u, 0u};
  if (base + 3 < n) {
    uint4 u = *(const uint4*)&deg[base];
    v[0] = u.x; v[1] = u.y; v[2] = u.z; v[3] = u.w;
  } else {
    for (int j = 0; j < 4; j++)
      if (base + j < n) v[j] = deg[base + j];
  }
  unsigned sum4 = v[0] + v[1] + v[2] + v[3];
  s[t] = sum4;
  __syncthreads();
  for (int off = 1; off < 256; off <<= 1) {
    unsigned add = (t >= off) ? s[t - off] : 0u;
    __syncthreads();
    s[t] += add;
    __syncthreads();
  }
  unsigned e = s[t] - sum4 + partial[blockIdx.x];
  for (int j = 0; j < 4; j++) {
    int i = base + j;
    if (i < n) {
      rowptr[i] = (int)e;
      cursor[i] = (int)e;
      if (i < NG) dis[i] = rsqrtf((float)v[j] + 1.0f);
      if (i == n - 1) rowptr[n] = (int)(e + v[j]);
      e += v[j];
    }
  }
}

// ---------------- fill body (XCD-sliced, nt edge reads) ----------------
__device__ __forceinline__ void fill_body(int blk, const int* ge, int Eg_,
                                          const int* de, int Ed_,
                                          const int* ce, int Ec_,
                                          int* __restrict__ cursor,
                                          int* __restrict__ adj) {
  const unsigned slice = blk & 7;
  const int chunk = blk >> 3;
  const unsigned lo = slice * SL;
  const int* src; const int* dst; int E, cb, mode; unsigned offD, offS;
  pick_chunk(chunk, ge, Eg_, de, Ed_, ce, Ec_, src, dst, E, cb, mode, offD, offS);
  int e0 = (cb << 10) + (int)threadIdx.x * 4;
  if (e0 >= E) return;
  i32x4 s4, d4;
  load4(src, dst, e0, E, s4, d4);
#pragma unroll
  for (int j = 0; j < 4; j++) {
    if (e0 + j >= E) break;
    unsigned nd = offD + (unsigned)d4[j];
    if (nd - lo < SL) {
      int p = atomicAdd(&cursor[nd], 1);
      adj[p] = s4[j];
    }
    if (mode != 0) {
      unsigned ns = offS + (unsigned)s4[j];
      if (ns - lo < SL) {
        int p = atomicAdd(&cursor[ns], 1);
        adj[p] = d4[j];
      }
    }
  }
}

// ---------------- MFMA f16 GEMM body: hh[M,128] = (X[M,128] @ W) * dis[row], f16 out ----------------
template <int INF16>
__device__ __forceinline__ void mgemm_body(char* lds, int bx, const void* __restrict__ Xv,
                                           const __half* __restrict__ Wt, int M,
                                           const float* __restrict__ dis,
                                           __half* __restrict__ hh) {
  char* As = lds;              // 64 x 128 f16 = 16 KB
  char* Bs = lds + 16 * 1024;  // 128 x 128 f16 = 32 KB
  const int t = threadIdx.x;
  const int row0 = bx * 64;

#pragma unroll
  for (int rep = 0; rep < 8; rep++) {
    int q = t + rep * 256;
    int r = q >> 4, c16 = (q & 15) * 16;
    uint4 v = *(const uint4*)((const char*)Wt + r * 256 + c16);
    *(uint4*)(Bs + ((r * 256 + c16) ^ ((r & 7) << 4))) = v;
  }
  if (INF16 == 0) {
    const float* X = (const float*)Xv;
#pragma unroll
    for (int rep = 0; rep < 8; rep++) {
      int q = t + rep * 256;
      int r = q >> 5, c4 = (q & 31) * 4;
      int gr = row0 + r;
      float4 xv = make_float4(0.f, 0.f, 0.f, 0.f);
      if (gr < M) xv = *(const float4*)&X[(size_t)gr * 128 + c4];
      __half2 h0 = __floats2half2_rn(xv.x, xv.y);
      __half2 h1 = __floats2half2_rn(xv.z, xv.w);
      uint2 pk;
      pk.x = *(unsigned*)&h0;
      pk.y = *(unsigned*)&h1;
      *(uint2*)(As + ((r * 256 + c4 * 2) ^ ((r & 7) << 4))) = pk;
    }
  } else {
    const __half* X = (const __half*)Xv;
#pragma unroll
    for (int rep = 0; rep < 4; rep++) {
      int q = t + rep * 256;
      int r = q >> 4, c16 = (q & 15) * 16;
      int gr = row0 + r;
      uint4 v = make_uint4(0u, 0u, 0u, 0u);
      if (gr < M) v = *(const uint4*)((const char*)X + (size_t)gr * 256 + c16);
      *(uint4*)(As + ((r * 256 + c16) ^ ((r & 7) << 4))) = v;
    }
  }
  __syncthreads();

  const int w = t >> 6, l = t & 63;
  const int lr = l & 15, lk = l >> 4;
  f32x4 acc[8] = {};
#pragma unroll
  for (int s = 0; s < 4; s++) {
    int arow = w * 16 + lr;
    f16x8 a = *(const f16x8*)(As + ((arow * 256 + lk * 16 + s * 64) ^ ((arow & 7) << 4)));
#pragma unroll
    for (int nt = 0; nt < 8; nt++) {
      int brow = nt * 16 + lr;
      f16x8 b = *(const f16x8*)(Bs + ((brow * 256 + lk * 16 + s * 64) ^ ((brow & 7) << 4)));
      acc[nt] = __builtin_amdgcn_mfma_f32_16x16x32_f16(a, b, acc[nt], 0, 0, 0);
    }
  }
  float ddv[4];
  int rowb = row0 + w * 16 + lk * 4;
#pragma unroll
  for (int j = 0; j < 4; j++) ddv[j] = (rowb + j < M) ? dis[rowb + j] : 0.f;
#pragma unroll
  for (int nt = 0; nt < 8; nt++) {
#pragma unroll
    for (int j = 0; j < 4; j++) {
      int row = rowb + j;
      if (row < M) hh[(size_t)row * 128 + nt * 16 + lr] = __float2half(acc[nt][j] * ddv[j]);
    }
  }
}

// ---------------- fill (sliced, nt) || GCN layer-1 MFMA GEMM ----------------
__global__ __launch_bounds__(256) void k_fillgemm(const int* __restrict__ ge, int Eg_,
                                                  const int* __restrict__ de, int Ed_,
                                                  const int* __restrict__ ce, int Ec_,
                                                  int* __restrict__ cursor,
                                                  int* __restrict__ adj,
                                                  const float* __restrict__ X,
                                                  const __half* __restrict__ Wt1,
                                                  const float* __restrict__ dis,
                                                  __half* __restrict__ hh) {
  __shared__ __align__(16) char lds[48 * 1024];
  const int nch = ((Eg_ + 1023) >> 10) + ((Ed_ + 1023) >> 10) + ((Ec_ + 1023) >> 10);
  const int nfill = nch * 8;
  if ((int)blockIdx.x < nfill) {
    fill_body(blockIdx.x, ge, Eg_, de, Ed_, ce, Ec_, cursor, adj);
    return;
  }
  mgemm_body<0>(lds, blockIdx.x - nfill, X, Wt1, NG, dis, hh);
}

// ---------------- standalone MFMA GEMM (layer 2, f16 input) ----------------
template <int INF16>
__global__ __launch_bounds__(256) void k_mgemm(const void* __restrict__ Xv,
                                               const __half* __restrict__ Wt, int M,
                                               const float* __restrict__ dis,
                                               __half* __restrict__ hh) {
  __shared__ __align__(16) char lds[48 * 1024];
  mgemm_body<INF16>(lds, blockIdx.x, Xv, Wt, M, dis, hh);
}

// ---------------- MFMA f16 GAT GEMM (drug+disease in one launch) ----------------
__global__ __launch_bounds__(256) void k_mgat(const float* __restrict__ Xd,
                                              const float* __restrict__ Xc,
                                              const __half* __restrict__ Wtd,
                                              const __half* __restrict__ Wtc,
                                              const float* __restrict__ attSd,
                                              const float* __restrict__ attSc,
                                              __half* __restrict__ hsd,
                                              __half* __restrict__ hsc,
                                              float* __restrict__ a_s_d,
                                              float* __restrict__ a_s_c) {
  __shared__ __align__(16) char lds[48 * 1024];
  char* As = lds;
  char* Bs = lds + 16 * 1024;
  const int t = threadIdx.x;
  const int nbd = (NDR + 63) >> 6;
  const int q = blockIdx.x >= nbd;
  const int bx = q ? blockIdx.x - nbd : blockIdx.x;
  const int M = q ? NDI : NDR;
  const float* X = q ? Xc : Xd;
  const __half* Wt = q ? Wtc : Wtd;
  const float* attS = q ? attSc : attSd;
  __half* hs = q ? hsc : hsd;
  float* a_s = q ? a_s_c : a_s_d;
  const int row0 = bx * 64;
  const int h = blockIdx.y;
  const __half* Wth = Wt + (size_t)h * 128 * 128;

#pragma unroll
  for (int rep = 0; rep < 8; rep++) {
    int r = (t + rep * 256) >> 4, c16 = ((t + rep * 256) & 15) * 16;
    uint4 v = *(const uint4*)((const char*)Wth + r * 256 + c16);
    *(uint4*)(Bs + ((r * 256 + c16) ^ ((r & 7) << 4))) = v;
  }
#pragma unroll
  for (int rep = 0; rep < 8; rep++) {
    int qq = t + rep * 256;
    int r = qq >> 5, c4 = (qq & 31) * 4;
    int gr = row0 + r;
    float4 xv = make_float4(0.f, 0.f, 0.f, 0.f);
    if (gr < M) xv = *(const float4*)&X[(size_t)gr * 128 + c4];
    __half2 h0 = __floats2half2_rn(xv.x, xv.y);
    __half2 h1 = __floats2half2_rn(xv.z, xv.w);
    uint2 pk;
    pk.x = *(unsigned*)&h0;
    pk.y = *(unsigned*)&h1;
    *(uint2*)(As + ((r * 256 + c4 * 2) ^ ((r & 7) << 4))) = pk;
  }
  __syncthreads();

  const int w = t >> 6, l = t & 63;
  const int lr = l & 15, lk = l >> 4;
  f32x4 acc[8] = {};
#pragma unroll
  for (int s = 0; s < 4; s++) {
    int arow = w * 16 + lr;
    f16x8 a = *(const f16x8*)(As + ((arow * 256 + lk * 16 + s * 64) ^ ((arow & 7) << 4)));
#pragma unroll
    for (int nt = 0; nt < 8; nt++) {
      int brow = nt * 16 + lr;
      f16x8 b = *(const f16x8*)(Bs + ((brow * 256 + lk * 16 + s * 64) ^ ((brow & 7) << 4)));
      acc[nt] = __builtin_amdgcn_mfma_f32_16x16x32_f16(a, b, acc[nt], 0, 0, 0);
    }
  }
  float av[8];
#pragma unroll
  for (int nt = 0; nt < 8; nt++) av[nt] = attS[h * 128 + nt * 16 + lr];

  int rowb = row0 + w * 16 + lk * 4;
  float p[4] = {0.f, 0.f, 0.f, 0.f};
#pragma unroll
  for (int nt = 0; nt < 8; nt++) {
#pragma unroll
    for (int j = 0; j < 4; j++) {
      int row = rowb + j;
      if (row < M) hs[(size_t)row * 512 + h * 128 + nt * 16 + lr] = __float2half(acc[nt][j]);
      p[j] += acc[nt][j] * av[nt];
    }
  }
#pragma unroll
  for (int m = 1; m < 16; m <<= 1) {
#pragma unroll
    for (int j = 0; j < 4; j++) p[j] += __shfl_xor(p[j], m);
  }
  if (lr == 0) {
#pragma unroll
    for (int j = 0; j < 4; j++) {
      int row = rowb + j;
      if (row < M) a_s[(size_t)row * 4 + h] = p[j];
    }
  }
}

// ---------------- GCN aggregation: CSR gather, wave/dst + ILP-8 ----------------
// FIN 1: out = x1 row f16; FIN 2: out = att row (8 scores fp32)
template <int FIN>
__global__ __launch_bounds__(256) void k_gather(const __half* __restrict__ hh,
                                                const int* __restrict__ rowptr,
                                                const int* __restrict__ adj,
                                                const float* __restrict__ dis,
                                                const float* __restrict__ b,
                                                const float* __restrict__ watt,
                                                void* __restrict__ outv, int n) {
  int wid = threadIdx.x >> 6;
  int lane = threadIdx.x & 63;
  int d = blockIdx.x * 4 + wid;
  if (d >= n) return;
  int p0 = rowptr[d], p1 = rowptr[d + 1];
  int c = lane * 2;
  float2 s;
  {
    unsigned v = *(const unsigned*)&hh[(size_t)d * 128 + c];  // self loop
    s = __half22float2(*(__half2*)&v);
  }
  for (int base = p0; base < p1; base += 64) {
    int remain = p1 - base;
    int m = remain < 64 ? remain : 64;
    int idx = (lane < m) ? adj[base + lane] : 0;
    int j = 0;
    for (; j + 8 <= m; j += 8) {
      int nb[8];
      unsigned v[8];
#pragma unroll
      for (int u = 0; u < 8; u++) nb[u] = __shfl(idx, j + u);
#pragma unroll
      for (int u = 0; u < 8; u++) v[u] = *(const unsigned*)&hh[(size_t)nb[u] * 128 + c];
#pragma unroll
      for (int u = 0; u < 8; u++) {
        float2 f = __half22float2(*(__half2*)&v[u]);
        s.x += f.x;
        s.y += f.y;
      }
    }
    for (; j + 4 <= m; j += 4) {
      int nb[4];
      unsigned v[4];
#pragma unroll
      for (int u = 0; u < 4; u++) nb[u] = __shfl(idx, j + u);
#pragma unroll
      for (int u = 0; u < 4; u++) v[u] = *(const unsigned*)&hh[(size_t)nb[u] * 128 + c];
#pragma unroll
      for (int u = 0; u < 4; u++) {
        float2 f = __half22float2(*(__half2*)&v[u]);
        s.x += f.x;
        s.y += f.y;
      }
    }
    for (; j < m; j++) {
      int nb = __shfl(idx, j);
      unsigned v = *(const unsigned*)&hh[(size_t)nb * 128 + c];
      float2 f = __half22float2(*(__half2*)&v);
      s.x += f.x;
      s.y += f.y;
    }
  }
  float dd = dis[d];
  float x0 = fmaxf(dd * s.x + b[c], 0.f);
  float x1v = fmaxf(dd * s.y + b[c + 1], 0.f);
  if (FIN == 1) {
    __half* o = (__half*)outv;
    __half2 hv = __floats2half2_rn(x0, x1v);
    *(__half2*)&o[(size_t)d * 128 + c] = hv;
  } else {
    float* o = (float*)outv;
    float p[8];
    const float* w0 = &watt[c * 8];
#pragma unroll
    for (int h = 0; h < 8; h++) p[h] = x0 * w0[h] + x1v * w0[8 + h];
#pragma unroll
    for (int mm = 32; mm; mm >>= 1) {
#pragma unroll
      for (int h = 0; h < 8; h++) p[h] += __shfl_xor(p[h], mm);
    }
    if (lane == 0) {
      *(float4*)&o[(size_t)d * 8] = make_float4(p[0], p[1], p[2], p[3]);
      *(float4*)&o[(size_t)d * 8 + 4] = make_float4(p[4], p[5], p[6], p[7]);
    }
  }
}

// ---------------- GAT softmax pass A: denom by dst-gather (regions at NG, 2NG) ----------------
__global__ __launch_bounds__(256) void k_edgeA(const int* __restrict__ rowptr,
                                               const int* __restrict__ adj,
                                               const float* __restrict__ a_s_d,
                                               const float* __restrict__ a_s_c,
                                               const float* __restrict__ att,
                                               float* __restrict__ denom_d,
                                               float* __restrict__ denom_c) {
  int nb1 = (NG + 255) >> 8;
  int blk = blockIdx.x;
  int q = blk >= nb1;
  int d = (blk - (q ? nb1 : 0)) * 256 + threadIdx.x;
  if (d >= NG) return;
  const int* rp = rowptr + NG + (q ? NG : 0);
  const float* a_s = q ? a_s_c : a_s_d;
  float* den = q ? denom_c : denom_d;
  int p0 = rp[d], p1 = rp[d + 1];
  float4 ad4 = *(const float4*)&att[(size_t)d * 8 + q * 4];
  float4 acc = make_float4(0.f, 0.f, 0.f, 0.f);
  for (int p = p0; p < p1; p++) {
    int s = adj[p];
    float4 as4 = *(const float4*)&a_s[(size_t)s * 4];
    float v0 = as4.x + ad4.x, v1 = as4.y + ad4.y, v2 = as4.z + ad4.z, v3 = as4.w + ad4.w;
    v0 = v0 > 0.f ? v0 : 0.2f * v0;
    v1 = v1 > 0.f ? v1 : 0.2f * v1;
    v2 = v2 > 0.f ? v2 : 0.2f * v2;
    v3 = v3 > 0.f ? v3 : 0.2f * v3;
    acc.x += __expf(fminf(v0, 50.f));
    acc.y += __expf(fminf(v1, 50.f));
    acc.z += __expf(fminf(v2, 50.f));
    acc.w += __expf(fminf(v3, 50.f));
  }
  *(float4*)&den[(size_t)d * 4] = acc;
}

// ---------------- GAT softmax pass B: wsrc by src-gather (regions at 3NG, 3NG+NDR) ----------------
__global__ __launch_bounds__(256) void k_edgeB(const int* __restrict__ rowptr,
                                               const int* __restrict__ adj,
                                               const float* __restrict__ a_s_d,
                                               const float* __restrict__ a_s_c,
                                               const float* __restrict__ att,
                                               const float* __restrict__ denom_d,
                                               const float* __restrict__ denom_c,
                                               float* __restrict__ wsrc_d,
                                               float* __restrict__ wsrc_c) {
  int gw = (blockIdx.x * 256 + threadIdx.x) >> 6;
  int lane = threadIdx.x & 63;
  int q = gw >= NDR;
  int s = q ? gw - NDR : gw;
  if (q && s >= NDI) return;
  const int* rp = rowptr + 3 * NG + (q ? NDR : 0);
  const float* a_s = q ? a_s_c : a_s_d;
  const float* den = q ? denom_c : denom_d;
  float* ws = q ? wsrc_c : wsrc_d;
  int p0 = rp[s], p1 = rp[s + 1];
  float4 as4 = *(const float4*)&a_s[(size_t)s * 4];
  int attoff = q * 4;
  float4 acc = make_float4(0.f, 0.f, 0.f, 0.f);
  for (int p = p0 + lane; p < p1; p += 64) {
    int d = adj[p];
    float4 ad4 = *(const float4*)&att[(size_t)d * 8 + attoff];
    float4 dn = *(const float4*)&den[(size_t)d * 4];
    float v0 = as4.x + ad4.x, v1 = as4.y + ad4.y, v2 = as4.z + ad4.z, v3 = as4.w + ad4.w;
    v0 = v0 > 0.f ? v0 : 0.2f * v0;
    v1 = v1 > 0.f ? v1 : 0.2f * v1;
    v2 = v2 > 0.f ? v2 : 0.2f * v2;
    v3 = v3 > 0.f ? v3 : 0.2f * v3;
    acc.x += __expf(fminf(v0, 50.f)) / (dn.x + 1e-16f);
    acc.y += __expf(fminf(v1, 50.f)) / (dn.y + 1e-16f);
    acc.z += __expf(fminf(v2, 50.f)) / (dn.z + 1e-16f);
    acc.w += __expf(fminf(v3, 50.f)) / (dn.w + 1e-16f);
  }
#pragma unroll
  for (int m = 1; m < 64; m <<= 1) {
    acc.x += __shfl_xor(acc.x, m);
    acc.y += __shfl_xor(acc.y, m);
    acc.z += __shfl_xor(acc.z, m);
    acc.w += __shfl_xor(acc.w, m);
  }
  if (lane == 0) *(float4*)&ws[(size_t)s * 4] = acc;
}

// ---------------- fused weighted column sums + embedding column sums ----------------
__global__ __launch_bounds__(512) void k_sum(const __half* __restrict__ hs_d,
                                             const float* __restrict__ wsrc_d,
                                             float* __restrict__ S_d,
                                             const __half* __restrict__ hs_c,
                                             const float* __restrict__ wsrc_c,
                                             float* __restrict__ S_c,
                                             const float* __restrict__ xd,
                                             float* __restrict__ od,
                                             const float* __restrict__ xc,
                                             float* __restrict__ oc) {
  int t = threadIdx.x;
  const int nws_d = (NDR + 63) >> 6;
  const int nws_c = (NDI + 63) >> 6;
  const int ncs_d = (NDR + 511) >> 9;
  int blk = blockIdx.x;
  if (blk < nws_d + nws_c) {
    int q = blk >= nws_d;
    const __half* hs = q ? hs_c : hs_d;
    const float* wsrc = q ? wsrc_c : wsrc_d;
    float* S = q ? S_c : S_d;
    int N = q ? NDI : NDR;
    int r0 = (q ? blk - nws_d : blk) * 64;
    int h = t >> 7;
    int r1 = min(r0 + 64, N);
    float acc = 0.f;
    for (int r = r0; r < r1; r++) acc += wsrc[r * 4 + h] * __half2float(hs[(size_t)r * 512 + t]);
    atomAddF(&S[t], acc);
  } else {
    int cb = blk - nws_d - nws_c;
    int q = cb >= ncs_d;
    const float* x = q ? xc : xd;
    float* o = q ? oc : od;
    int N = q ? NDI : NDR;
    int r0 = (q ? cb - ncs_d : cb) * 512 + (t >> 7) * 128;
    int col = t & 127;
    int r1 = min(r0 + 128, N);
    float acc = 0.f;
    for (int r = r0; r < r1; r++) acc += x[(size_t)r * 128 + col];
    if (r0 < N) atomAddF(&o[col], acc);
  }
}

// ---------------- final fuse ----------------
__global__ __launch_bounds__(128) void k_final(const float* __restrict__ S_d,
                                               const float* __restrict__ S_c,
                                               const float* __restrict__ bdsum,
                                               const float* __restrict__ bcsum,
                                               const float* __restrict__ bd_bias,
                                               const float* __restrict__ bc_bias,
                                               const float* __restrict__ fuse_w,
                                               const float* __restrict__ fuse_b,
                                               float* __restrict__ out) {
  __shared__ float cat[384];
  int t = threadIdx.x;
  float sd = S_d[t] + S_d[128 + t] + S_d[256 + t] + S_d[384 + t];
  float sc = S_c[t] + S_c[128 + t] + S_c[256 + t] + S_c[384 + t];
  const float inv = 1.0f / (4.0f * (float)NG);
  cat[t] = 0.5f * (sd * inv + bd_bias[t] + sc * inv + bc_bias[t]);
  cat[128 + t] = bdsum[t] * (1.0f / (float)NDR);
  cat[256 + t] = bcsum[t] * (1.0f / (float)NDI);
  __syncthreads();
  float o = fuse_b[t];
  for (int k = 0; k < 384; k++) o += cat[k] * fuse_w[k * 128 + t];
  out[t] = o;
}

// ---------------- host launch ----------------
extern "C" void kernel_launch(void* const* d_in, const int* in_sizes, int n_in,
                              void* d_out, int out_size, void* d_ws, size_t ws_size,
                              hipStream_t stream) {
  const float* gene_nodes   = (const float*)d_in[0];
  const int*   drug_edges   = (const int*)d_in[1];
  const int*   dise_edges   = (const int*)d_in[2];
  const int*   gene_edges   = (const int*)d_in[3];
  const float* gcn1_w       = (const float*)d_in[4];
  const float* gcn1_b       = (const float*)d_in[5];
  const float* gcn2_w       = (const float*)d_in[6];
  const float* gcn2_b       = (const float*)d_in[7];
  const float* drug_embed   = (const float*)d_in[8];
  const float* dise_embed   = (const float*)d_in[9];
  const float* gat_d_w      = (const float*)d_in[10];
  const float* gat_d_att_s  = (const float*)d_in[11];
  const float* gat_d_att_d  = (const float*)d_in[12];
  const float* gat_d_b      = (const float*)d_in[13];
  const float* gat_c_w      = (const float*)d_in[14];
  const float* gat_c_att_s  = (const float*)d_in[15];
  const float* gat_c_att_d  = (const float*)d_in[16];
  const float* gat_c_b      = (const float*)d_in[17];
  const float* fuse_w       = (const float*)d_in[18];
  const float* fuse_b       = (const float*)d_in[19];
  const int Ed = in_sizes[1] / 2;
  const int Ec = in_sizes[2] / 2;
  const int Eg = in_sizes[3] / 2;
  float* out = (float*)d_out;
  (void)n_in; (void)out_size; (void)ws_size;

  const int NBS = cdiv_h(NDOM, 1024);   // 308 scan blocks
  const int nch = cdiv_h(Eg, 1024) + cdiv_h(Ed, 1024) + cdiv_h(Ec, 1024);

  // workspace layout (zero-init region first, single memset)
  char* w = (char*)d_ws;
  auto alloc = [&](size_t n) {
    char* p = w;
    w += (n + 511) & ~(size_t)511;
    return p;
  };
  char* z0 = w;
  unsigned* deg     = (unsigned*)alloc((size_t)NDOM * 4);
  float* S_d        = (float*)alloc(512 * 4);
  float* S_c        = (float*)alloc(512 * 4);
  float* bdsum      = (float*)alloc(512);
  float* bcsum      = (float*)alloc(512);
  size_t zbytes = (size_t)(w - z0);
  float* denom_d    = (float*)alloc((size_t)NG * 16);
  float* denom_c    = (float*)alloc((size_t)NG * 16);
  float* wsrc_d     = (float*)alloc((size_t)NDR * 16);
  float* wsrc_c     = (float*)alloc((size_t)NDI * 16);
  float* dis        = (float*)alloc((size_t)NG * 4);
  float* watt       = (float*)alloc(128 * 8 * 4);
  float* att        = (float*)alloc((size_t)NG * 8 * 4);
  float* a_s_d      = (float*)alloc((size_t)NDR * 16);
  float* a_s_c      = (float*)alloc((size_t)NDI * 16);
  unsigned* partial = (unsigned*)alloc((size_t)512 * 4);
  int* rowptr       = (int*)alloc((size_t)(NDOM + 1) * 4);
  int* cursor       = (int*)alloc((size_t)NDOM * 4);
  int* adj          = (int*)alloc((size_t)(Eg + 2 * (Ed + Ec)) * 4);
  __half* Wt1       = (__half*)alloc((size_t)128 * 128 * 2);
  __half* Wt2       = (__half*)alloc((size_t)128 * 128 * 2);
  __half* Wtd       = (__half*)alloc((size_t)512 * 128 * 2);
  __half* Wtc       = (__half*)alloc((size_t)512 * 128 * 2);
  __half* hh        = (__half*)alloc((size_t)NG * 128 * 2);
  __half* x1        = (__half*)alloc((size_t)NG * 128 * 2);
  __half* hs_d      = (__half*)alloc((size_t)NDR * 512 * 2);
  __half* hs_c      = (__half*)alloc((size_t)NDI * 512 * 2);

  hipMemsetAsync(z0, 0, zbytes, stream);

  // front: unsliced degree (nt loads) || weight prep
  k_front<<<nch + 11, 256, 0, stream>>>(gene_edges, Eg, drug_edges, Ed, dise_edges, Ec, deg,
                                        gcn1_w, gcn2_w, gat_d_w, gat_c_w, gat_d_att_d, gat_c_att_d,
                                        Wt1, Wt2, Wtd, Wtc, watt);
  // scan -> rowptr(+cursor,+dis)
  k_blocksum4<<<NBS, 256, 0, stream>>>(deg, partial, NDOM);
  k_scanpart<<<1, 512, 0, stream>>>(partial, NBS);
  k_rowptrAll<<<NBS, 256, 0, stream>>>(deg, partial, NDOM, rowptr, cursor, dis);

  // sliced fill (nt loads) || GCN layer-1 MFMA GEMM (both depend only on rowptr/dis)
  k_fillgemm<<<nch * 8 + cdiv_h(NG, 64), 256, 0, stream>>>(gene_edges, Eg, drug_edges, Ed,
                                                           dise_edges, Ec, cursor, adj,
                                                           gene_nodes, Wt1, dis, hh);

  // GCN layer 1 aggregation
  k_gather<1><<<cdiv_h(NG, 4), 256, 0, stream>>>(hh, rowptr, adj, dis, gcn1_b, nullptr, x1, NG);

  // GCN layer 2 (f16 input; att-score epilogue; x2 never materialized)
  k_mgemm<1><<<cdiv_h(NG, 64), 256, 0, stream>>>(x1, Wt2, NG, dis, hh);
  k_gather<2><<<cdiv_h(NG, 4), 256, 0, stream>>>(hh, rowptr, adj, dis, gcn2_b, watt, att, NG);

  // GAT source transforms (both graphs, one launch)
  k_mgat<<<dim3(cdiv_h(NDR, 64) + cdiv_h(NDI, 64), 4), 256, 0, stream>>>(
      drug_embed, dise_embed, Wtd, Wtc, gat_d_att_s, gat_c_att_s, hs_d, hs_c, a_s_d, a_s_c);

  // GAT softmax: denom by dst-gather, wsrc by src-gather (no atomics)
  k_edgeA<<<2 * cdiv_h(NG, 256), 256, 0, stream>>>(rowptr, adj, a_s_d, a_s_c, att, denom_d, denom_c);
  k_edgeB<<<cdiv_h((NDR + NDI) * 64, 256), 256, 0, stream>>>(rowptr, adj, a_s_d, a_s_c, att,
                                                             denom_d, denom_c, wsrc_d, wsrc_c);

  // fused weighted column sums + embedding means
  int nsum = (cdiv_h(NDR, 64) + cdiv_h(NDI, 64)) + (cdiv_h(NDR, 512) + cdiv_h(NDI, 512));
  k_sum<<<nsum, 512, 0, stream>>>(hs_d, wsrc_d, S_d, hs_c, wsrc_c, S_c,
                                  drug_embed, bdsum, dise_embed, bcsum);

  // final fuse
  k_final<<<1, 128, 0, stream>>>(S_d, S_c, bdsum, bcsum, gat_d_b, gat_c_b, fuse_w, fuse_b, out);
}